// Round 9
// baseline (355.235 us; speedup 1.0000x reference)
//
#include <hip/hip_runtime.h>
#include <hip/hip_fp16.h>
#include <math.h>

// ---------------------------------------------------------------------------
// GCN 3-layer forward, round 19 (= round 18 + W3-transpose + lin2 2-tiles).
// out[i] = dinv[i] * ( sum_{e:dst=i} Hs[src] + Hs[i] ) + b,  Hs = (X@W)*dinv.
// Round-19 delta vs round-18 (344.5us):
//  - agg64w3: W3 staged TRANSPOSED [q][64] -> projection reads at stride-8
//    across f8-groups = 2-way bank aliasing (free) instead of 4-way conflicts
//    (SQ_LDS_BANK_CONFLICT was 4.8M ~ 8us of the kernel's 74us).
//  - lin2: 2 node-tiles/WG (782 WGs; 391 was ~1.5 waves/SIMD, K=64 MFMA had
//    no latency cover).
// ---------------------------------------------------------------------------

#define WS_ALIGN(x) (((x) + 255) & ~(size_t)255)
#define BKN 256                 // nodes per bin/sort bucket
#define CAP 9216                // slab capacity per bucket (mean 8184; +11 sigma)
#define EPT 8                   // edges per thread in bin kernel
#define BIN_THR 512
#define BIN_CHUNK (BIN_THR * EPT)  // 4096 edges per WG

typedef _Float16 half8 __attribute__((ext_vector_type(8)));
typedef float floatx4 __attribute__((ext_vector_type(4)));

// ---------------- fat: bin (blocks [0,binG)) || lin1 (blocks [binG,+linG)) ----------------
__global__ __launch_bounds__(512) void fat_bin_lin1_kernel(
    const int* __restrict__ src, const int* __restrict__ dst,
    int* __restrict__ cur, int* __restrict__ slab, int E, int NB, int binG,
    const float* __restrict__ Xf, const float* __restrict__ W1,
    _Float16* __restrict__ Y, int n) {
    __shared__ int smem[5632];   // bin: cnt/incl/gbase[512]x3 + stag[4096] = 22.5KB
    const int tid = threadIdx.x;
    if (blockIdx.x < binG) {
        // ---------------- bin role (round-15 LDS counting sort) ----------------
        int* cnt   = smem;
        int* incl  = smem + 512;
        int* gbase = smem + 1024;
        int* stag  = smem + 1536;
        const int base = blockIdx.x * BIN_CHUNK + tid * EPT;
        cnt[tid] = 0;
        __syncthreads();
        int b[EPT], w[EPT], lp[EPT];
        #pragma unroll
        for (int k = 0; k < EPT; ++k) {
            int e = base + k;
            if (e < E) {
                int s = src[e], d = dst[e];
                b[k] = d >> 8;
                w[k] = (s << 8) | (d & 255);
            } else b[k] = -1;
        }
        #pragma unroll
        for (int k = 0; k < EPT; ++k)
            if (b[k] >= 0) lp[k] = atomicAdd(&cnt[b[k]], 1);
        __syncthreads();
        incl[tid] = cnt[tid];
        __syncthreads();
        for (int off = 1; off < 512; off <<= 1) {
            int v = 0;
            if (tid >= off) v = incl[tid - off];
            __syncthreads();
            incl[tid] += v;
            __syncthreads();
        }
        if (tid < NB) {
            int c = cnt[tid];
            gbase[tid] = c ? atomicAdd(&cur[tid], c) : 0;
        }
        #pragma unroll
        for (int k = 0; k < EPT; ++k)
            if (b[k] >= 0) stag[incl[b[k]] - cnt[b[k]] + lp[k]] = w[k];
        __syncthreads();
        const int total = incl[NB - 1];
        for (int idx = tid; idx < total; idx += BIN_THR) {
            int wv = stag[idx];
            int lo = 0, hi = NB - 1;
            while (lo < hi) { int mid = (lo + hi) >> 1; if (incl[mid] > idx) hi = mid; else lo = mid + 1; }
            int excl = incl[lo] - cnt[lo];
            int p = gbase[lo] + (idx - excl);
            if (p < CAP) slab[(size_t)lo * CAP + p] = wv;
        }
    } else {
        // ---------------- lin1 role: Y16 = fp16(X @ W1), UNSCALED ----------------
        constexpr int K = 128, KC = 4;
        _Float16* Bf = (_Float16*)smem;   // 16KB B-fragment staging
        for (int i = tid; i < KC * 4 * 64 * 8; i += 512) {
            int j = i & 7, lane = (i >> 3) & 63, tile = (i >> 9) & 3, kc = i >> 11;
            int k = kc * 32 + ((lane >> 4) << 3) + j;
            int col = tile * 16 + (lane & 15);
            Bf[i] = (_Float16)W1[k * 64 + col];
        }
        __syncthreads();
        const int lane = tid & 63, wid = tid >> 6;   // 8 waves
        const int mrow = lane & 15, quad = lane >> 4;
        const int lblk = blockIdx.x - binG;
        #pragma unroll
        for (int tt = 0; tt < 2; ++tt) {             // 8 waves x 2 groups = 256 nodes
            const int base = lblk * 256 + wid * 32 + tt * 16;
            if (base >= n) continue;
            const int anode = min(base + mrow, n - 1);
            floatx4 acc[4] = {{0, 0, 0, 0}, {0, 0, 0, 0}, {0, 0, 0, 0}, {0, 0, 0, 0}};
            #pragma unroll
            for (int kc = 0; kc < KC; ++kc) {
                float4 xa = *(const float4*)&Xf[(size_t)anode * K + kc * 32 + quad * 8];
                float4 xb = *(const float4*)&Xf[(size_t)anode * K + kc * 32 + quad * 8 + 4];
                half8 a;
                a[0] = (_Float16)xa.x; a[1] = (_Float16)xa.y; a[2] = (_Float16)xa.z; a[3] = (_Float16)xa.w;
                a[4] = (_Float16)xb.x; a[5] = (_Float16)xb.y; a[6] = (_Float16)xb.z; a[7] = (_Float16)xb.w;
                #pragma unroll
                for (int t = 0; t < 4; ++t) {
                    half8 b = *(const half8*)&Bf[((kc * 4 + t) * 64 + lane) * 8];
                    acc[t] = __builtin_amdgcn_mfma_f32_16x16x32_f16(a, b, acc[t], 0, 0, 0);
                }
            }
            #pragma unroll
            for (int r = 0; r < 4; ++r) {
                int node = base + quad * 4 + r;
                if (node < n) {
                    #pragma unroll
                    for (int t = 0; t < 4; ++t)
                        Y[(size_t)node * 64 + t * 16 + mrow] = (_Float16)acc[t][r];
                }
            }
        }
    }
}

// ---------------- per-bucket counting sort -> per-node CSR + dinv ----------------
__global__ __launch_bounds__(512) void bucket_sort_kernel(
    const int* __restrict__ slab, const int* __restrict__ cur,
    int* __restrict__ srcS, int2* __restrict__ rows,
    float* __restrict__ dinv, int n) {
    __shared__ int cnt[BKN], s[BKN], cursor[BKN];
    const int b = blockIdx.x, tid = threadIdx.x;
    const int m = min(cur[b], CAP);
    const int* sp = slab + (size_t)b * CAP;
    if (tid < BKN) cnt[tid] = 0;
    __syncthreads();
    for (int j = tid; j < m; j += 512) atomicAdd(&cnt[sp[j] & (BKN - 1)], 1);
    __syncthreads();
    if (tid < BKN) s[tid] = cnt[tid];
    __syncthreads();
    for (int off = 1; off < BKN; off <<= 1) {
        int v = 0;
        if (tid < BKN && tid >= off) v = s[tid - off];
        __syncthreads();
        if (tid < BKN) s[tid] += v;
        __syncthreads();
    }
    if (tid < BKN) {
        int ofs = s[tid] - cnt[tid];
        cursor[tid] = ofs;
        int node = b * BKN + tid;
        if (node < n) {
            rows[node] = make_int2(b * CAP + ofs, b * CAP + ofs + cnt[tid]);
            dinv[node] = rsqrtf((float)(cnt[tid] + 1));
        }
    }
    __syncthreads();
    for (int j = tid; j < m; j += 512) {
        int w = sp[j];
        int p = atomicAdd(&cursor[w & (BKN - 1)], 1);
        srcS[(size_t)b * CAP + p] = w >> 8;
    }
}

// ---------------- MFMA linear (fp16 input), K=64, 2 tiles per WG ----------------
__global__ __launch_bounds__(256) void linear_mfma_f16_kernel(
    const _Float16* __restrict__ Xh, const float* __restrict__ W,
    const float* __restrict__ dinv, _Float16* __restrict__ Y, int n) {
    constexpr int K = 64, KC = 2;
    __shared__ _Float16 Bf[KC * 4 * 64 * 8];  // 8KB
    const int tid = threadIdx.x;
    for (int i = tid; i < KC * 4 * 64 * 8; i += 256) {
        int j = i & 7, lane = (i >> 3) & 63, tile = (i >> 9) & 3, kc = i >> 11;
        int k = kc * 32 + ((lane >> 4) << 3) + j;
        int col = tile * 16 + (lane & 15);
        Bf[i] = (_Float16)W[k * 64 + col];
    }
    __syncthreads();
    const int lane = tid & 63, wid = tid >> 6;
    const int mrow = lane & 15, quad = lane >> 4;
    #pragma unroll
    for (int tt = 0; tt < 2; ++tt) {
        const int base = (blockIdx.x * 2 + tt) * 64 + wid * 16;
        if (base >= n) continue;
        const int anode = min(base + mrow, n - 1);
        floatx4 acc[4] = {{0, 0, 0, 0}, {0, 0, 0, 0}, {0, 0, 0, 0}, {0, 0, 0, 0}};
        #pragma unroll
        for (int kc = 0; kc < KC; ++kc) {
            half8 a = *(const half8*)&Xh[(size_t)anode * K + kc * 32 + quad * 8];
            #pragma unroll
            for (int t = 0; t < 4; ++t) {
                half8 b = *(const half8*)&Bf[((kc * 4 + t) * 64 + lane) * 8];
                acc[t] = __builtin_amdgcn_mfma_f32_16x16x32_f16(a, b, acc[t], 0, 0, 0);
            }
        }
        #pragma unroll
        for (int r = 0; r < 4; ++r) {
            int node = base + quad * 4 + r;
            if (node < n) {
                float di = dinv[node];
                #pragma unroll
                for (int t = 0; t < 4; ++t)
                    Y[(size_t)node * 64 + t * 16 + mrow] = (_Float16)(acc[t][r] * di);
            }
        }
    }
}

// ---------------- agg64s (L1): gather UNSCALED h1, scale by dinv[src] in-loop ----------------
// out[i] = relu( (sum_s dinv_s*h1[s] + dinv_i*h1[i]) * dinv_i + b1 )
__global__ __launch_bounds__(256) void agg64s_kernel(
    const _Float16* __restrict__ H1, const float* __restrict__ dinv,
    const int* __restrict__ srcS, const int2* __restrict__ rows,
    const float* __restrict__ bias, _Float16* __restrict__ Out, int n) {
    const int wave = (blockIdx.x * blockDim.x + threadIdx.x) >> 6;
    const int lane = threadIdx.x & 63;
    if (wave >= n) return;
    const int slot = lane >> 3;  // edge slot 0..7
    const int f8 = lane & 7;     // feat slice [f8*8, f8*8+8)
    const int2 row = rows[wave];
    const int beg = row.x, end = row.y;
    half8 hA, hB;
    #pragma unroll
    for (int i = 0; i < 8; ++i) { hA[i] = (_Float16)0.f; hB[i] = (_Float16)0.f; }
    int j = beg;
    for (; j + 32 <= end; j += 32) {      // 32 edges: 4 gathers in flight
        int s0 = srcS[j      + slot];
        int s1 = srcS[j + 8  + slot];
        int s2 = srcS[j + 16 + slot];
        int s3 = srcS[j + 24 + slot];
        _Float16 d0 = (_Float16)dinv[s0];
        _Float16 d1 = (_Float16)dinv[s1];
        _Float16 d2 = (_Float16)dinv[s2];
        _Float16 d3 = (_Float16)dinv[s3];
        half8 v0 = *(const half8*)&H1[(size_t)s0 * 64 + f8 * 8];
        half8 v1 = *(const half8*)&H1[(size_t)s1 * 64 + f8 * 8];
        half8 v2 = *(const half8*)&H1[(size_t)s2 * 64 + f8 * 8];
        half8 v3 = *(const half8*)&H1[(size_t)s3 * 64 + f8 * 8];
        hA += v0 * d0; hB += v1 * d1; hA += v2 * d2; hB += v3 * d3;
    }
    for (; j + 16 <= end; j += 16) {      // 16 edges
        int s0 = srcS[j + slot];
        int s1 = srcS[j + 8 + slot];
        _Float16 d0 = (_Float16)dinv[s0];
        _Float16 d1 = (_Float16)dinv[s1];
        half8 v0 = *(const half8*)&H1[(size_t)s0 * 64 + f8 * 8];
        half8 v1 = *(const half8*)&H1[(size_t)s1 * 64 + f8 * 8];
        hA += v0 * d0; hB += v1 * d1;
    }
    for (; j < end; j += 8) {             // tail (exec-masked)
        int jj = j + slot;
        if (jj < end) {
            int s0 = srcS[jj];
            _Float16 d0 = (_Float16)dinv[s0];
            half8 v = *(const half8*)&H1[(size_t)s0 * 64 + f8 * 8];
            hA += v * d0;
        }
    }
    half8 ht = hA + hB;
    #pragma unroll
    for (int mask = 8; mask <= 32; mask <<= 1) {  // packed fold over slots
        int4 ci = *(int4*)&ht, oi;
        oi.x = __shfl_xor(ci.x, mask);
        oi.y = __shfl_xor(ci.y, mask);
        oi.z = __shfl_xor(ci.z, mask);
        oi.w = __shfl_xor(ci.w, mask);
        ht += *(half8*)&oi;
    }
    half8 self = *(const half8*)&H1[(size_t)wave * 64 + f8 * 8];
    const float di = dinv[wave];
    float4 b0 = *(const float4*)&bias[f8 * 8];
    float4 b1v = *(const float4*)&bias[f8 * 8 + 4];
    float bb[8] = {b0.x, b0.y, b0.z, b0.w, b1v.x, b1v.y, b1v.z, b1v.w};
    half8 o;
    #pragma unroll
    for (int i = 0; i < 8; ++i) {
        float t = ((float)ht[i] + di * (float)self[i]) * di + bb[i];
        o[i] = (_Float16)fmaxf(t, 0.f);
    }
    if (slot == 0) *(half8*)&Out[(size_t)wave * 64 + f8 * 8] = o;
}

// ---------------- agg64w3 (L2): aggregate Hs2 + relu -> h2, project W3, write hsC ----------------
// h2[f] = relu( (sum_s Hs2[s] + Hs2[i]) * di + b2[f] );  hsC[i][q] = di * sum_f h2[f] W3[f][q]
// W3 staged transposed [q][64]: projection reads are 2-way bank aliasing (free).
__global__ __launch_bounds__(256) void agg64w3_kernel(
    const _Float16* __restrict__ Hs, const float* __restrict__ dinv,
    const int* __restrict__ srcS, const int2* __restrict__ rows,
    const float* __restrict__ bias, const float* __restrict__ W3,
    __half* __restrict__ Yc, int n) {
    __shared__ float W3t[6 * 64];   // W3t[q*64 + f] = W3[f*6 + q]
    const int tid = threadIdx.x;
    for (int i = tid; i < 6 * 64; i += 256) {
        int q = i >> 6, f = i & 63;
        W3t[i] = W3[f * 6 + q];
    }
    __syncthreads();
    const int wave = (blockIdx.x * blockDim.x + tid) >> 6;
    const int lane = tid & 63;
    if (wave >= n) return;
    const int slot = lane >> 3;
    const int f8 = lane & 7;
    const int2 row = rows[wave];
    const int beg = row.x, end = row.y;
    half8 hA, hB;
    #pragma unroll
    for (int i = 0; i < 8; ++i) { hA[i] = (_Float16)0.f; hB[i] = (_Float16)0.f; }
    int j = beg;
    for (; j + 32 <= end; j += 32) {
        int s0 = srcS[j      + slot];
        int s1 = srcS[j + 8  + slot];
        int s2 = srcS[j + 16 + slot];
        int s3 = srcS[j + 24 + slot];
        half8 v0 = *(const half8*)&Hs[(size_t)s0 * 64 + f8 * 8];
        half8 v1 = *(const half8*)&Hs[(size_t)s1 * 64 + f8 * 8];
        half8 v2 = *(const half8*)&Hs[(size_t)s2 * 64 + f8 * 8];
        half8 v3 = *(const half8*)&Hs[(size_t)s3 * 64 + f8 * 8];
        hA += v0; hB += v1; hA += v2; hB += v3;
    }
    for (; j + 16 <= end; j += 16) {
        int s0 = srcS[j + slot];
        int s1 = srcS[j + 8 + slot];
        half8 v0 = *(const half8*)&Hs[(size_t)s0 * 64 + f8 * 8];
        half8 v1 = *(const half8*)&Hs[(size_t)s1 * 64 + f8 * 8];
        hA += v0; hB += v1;
    }
    for (; j < end; j += 8) {
        int jj = j + slot;
        if (jj < end) {
            half8 v = *(const half8*)&Hs[(size_t)srcS[jj] * 64 + f8 * 8];
            hA += v;
        }
    }
    half8 ht = hA + hB;
    #pragma unroll
    for (int mask = 8; mask <= 32; mask <<= 1) {
        int4 ci = *(int4*)&ht, oi;
        oi.x = __shfl_xor(ci.x, mask);
        oi.y = __shfl_xor(ci.y, mask);
        oi.z = __shfl_xor(ci.z, mask);
        oi.w = __shfl_xor(ci.w, mask);
        ht += *(half8*)&oi;
    }
    half8 self = *(const half8*)&Hs[(size_t)wave * 64 + f8 * 8];
    const float di = dinv[wave];
    float4 b0 = *(const float4*)&bias[f8 * 8];
    float4 b1v = *(const float4*)&bias[f8 * 8 + 4];
    float bb[8] = {b0.x, b0.y, b0.z, b0.w, b1v.x, b1v.y, b1v.z, b1v.w};
    // h2 for this lane's 8 feats, then W3 partial projection (transposed reads)
    float p[6] = {0.f, 0.f, 0.f, 0.f, 0.f, 0.f};
    #pragma unroll
    for (int i = 0; i < 8; ++i) {
        float h2 = fmaxf(((float)ht[i] + (float)self[i]) * di + bb[i], 0.f);
        #pragma unroll
        for (int q = 0; q < 6; ++q) p[q] = fmaf(h2, W3t[q * 64 + f8 * 8 + i], p[q]);
    }
    #pragma unroll
    for (int mask = 1; mask <= 4; mask <<= 1) {   // fold over f8 (bits 0..2)
        #pragma unroll
        for (int q = 0; q < 6; ++q) p[q] += __shfl_xor(p[q], mask);
    }
    if (lane == 0) {
        half8 o;
        #pragma unroll
        for (int q = 0; q < 6; ++q) o[q] = (_Float16)(p[q] * di);
        o[6] = (_Float16)0.f; o[7] = (_Float16)0.f;
        *(half8*)&Yc[(size_t)wave * 8] = o;
    }
}

// ---------------- aggregate 6 feats + bias + log_softmax: lane-per-edge ----------------
__global__ __launch_bounds__(256) void agg6_lsm_kernel(
    const _Float16* __restrict__ Hs6, const float* __restrict__ dinv,
    const int* __restrict__ srcS, const int2* __restrict__ rows,
    const float* __restrict__ bias, float* __restrict__ out, int n) {
    const int wave = (blockIdx.x * blockDim.x + threadIdx.x) >> 6;
    const int lane = threadIdx.x & 63;
    if (wave >= n) return;
    const int2 row = rows[wave];
    const int beg = row.x, end = row.y;
    half8 ht;
    #pragma unroll
    for (int i = 0; i < 8; ++i) ht[i] = (_Float16)0.f;
    for (int j = beg + lane; j < end; j += 64) {          // 1 iter typ. (deg~32)
        int s = srcS[j];
        ht += *(const half8*)&Hs6[(size_t)s * 8];          // 16B row gather
    }
    #pragma unroll
    for (int mask = 1; mask <= 32; mask <<= 1) {          // packed fold, 64 lanes
        int4 ci = *(int4*)&ht, oi;
        oi.x = __shfl_xor(ci.x, mask);
        oi.y = __shfl_xor(ci.y, mask);
        oi.z = __shfl_xor(ci.z, mask);
        oi.w = __shfl_xor(ci.w, mask);
        ht += *(half8*)&oi;
    }
    half8 self = *(const half8*)&Hs6[(size_t)wave * 8];
    const float di = dinv[wave];
    float a[6];
    #pragma unroll
    for (int q = 0; q < 6; ++q)
        a[q] = ((float)ht[q] + (float)self[q]) * di + bias[q];
    float mx = a[0];
    #pragma unroll
    for (int q = 1; q < 6; ++q) mx = fmaxf(mx, a[q]);
    float sum = 0.f;
    #pragma unroll
    for (int q = 0; q < 6; ++q) sum += expf(a[q] - mx);
    float lse = mx + logf(sum);
    if (lane == 0) {
        float* op = &out[(size_t)wave * 6];
        *(float2*)(op)     = make_float2(a[0] - lse, a[1] - lse);
        *(float2*)(op + 2) = make_float2(a[2] - lse, a[3] - lse);
        *(float2*)(op + 4) = make_float2(a[4] - lse, a[5] - lse);
    }
}

// ---------------------------------------------------------------------------
extern "C" void kernel_launch(void* const* d_in, const int* in_sizes, int n_in,
                              void* d_out, int out_size, void* d_ws, size_t ws_size,
                              hipStream_t stream) {
    const float* x  = (const float*)d_in[0];
    const int*   ei = (const int*)d_in[1];
    const float* W1 = (const float*)d_in[2];
    const float* b1 = (const float*)d_in[3];
    const float* W2 = (const float*)d_in[4];
    const float* b2 = (const float*)d_in[5];
    const float* W3 = (const float*)d_in[6];
    const float* b3 = (const float*)d_in[7];
    float* out = (float*)d_out;

    const int n = in_sizes[0] / 128;  // 100000
    const int E = in_sizes[1] / 2;    // 3200000
    const int* src = ei;
    const int* dst = ei + E;
    const int NB = (n + BKN - 1) / BKN;  // 391

    // ---- workspace carve ----
    char* ws = (char*)d_ws;
    auto carve = [&](size_t bytes) { char* p = ws; ws += WS_ALIGN(bytes); return p; };
    int*      cur  = (int*)     carve((size_t)NB * 4);
    float*    dinv = (float*)   carve((size_t)n * 4);
    int*      slab = (int*)     carve((size_t)NB * CAP * 4);   // 14.4 MB
    int*      srcS = (int*)     carve((size_t)NB * CAP * 4);   // 14.4 MB
    int2*     rows = (int2*)    carve((size_t)n * 8);
    _Float16* hsA  = (_Float16*)carve((size_t)n * 64 * 2 + 4096);   // 12.8 MB
    _Float16* hsB  = (_Float16*)carve((size_t)n * 64 * 2 + 4096);   // 12.8 MB
    _Float16* hsC  = (_Float16*)carve((size_t)n * 8 * 2);           // 1.6 MB
    (void)ws_size; (void)n_in; (void)out_size;

    const int binG = (E + BIN_CHUNK - 1) / BIN_CHUNK;   // 782
    const int linG = (n + 255) / 256;                   // 391
    const int aggGrid = (n + 3) / 4;

    // ---- CSR phase 1 || layer-1 linear (independent after dinv decoupling) ----
    (void)hipMemsetAsync(cur, 0, (size_t)NB * 4, stream);
    fat_bin_lin1_kernel<<<binG + linG, 512, 0, stream>>>(
        src, dst, cur, slab, E, NB, binG, x, W1, hsA, n);

    // ---- CSR phase 2 ----
    bucket_sort_kernel<<<NB, 512, 0, stream>>>(slab, cur, srcS, rows, dinv, n);

    // ---- layer 1 aggregation (dinv[src] applied in-loop) ----
    agg64s_kernel<<<aggGrid, 256, 0, stream>>>(hsA, dinv, srcS, rows, b1, hsB, n);

    // ---- layer 2 linear ----
    linear_mfma_f16_kernel<<<(n + 127) / 128, 256, 0, stream>>>(hsB, W2, dinv, hsA, n);

    // ---- layer 2 aggregation + fused W3 projection ----
    agg64w3_kernel<<<aggGrid, 256, 0, stream>>>(hsA, dinv, srcS, rows, b2, W3, (__half*)hsC, n);

    // ---- layer 3 aggregation + log_softmax ----
    agg6_lsm_kernel<<<aggGrid, 256, 0, stream>>>(hsC, dinv, srcS, rows, b3, out, n);
}

// Round 10
// 350.517 us; speedup vs baseline: 1.0135x; 1.0135x over previous
//
#include <hip/hip_runtime.h>
#include <hip/hip_fp16.h>
#include <math.h>

// ---------------------------------------------------------------------------
// GCN 3-layer forward, round 20 (= round 18 + conflict-free ALIGNED W3 stage).
// out[i] = dinv[i] * ( sum_{e:dst=i} Hs[src] + Hs[i] ) + b,  Hs = (X@W)*dinv.
// Round-20 delta vs round-18 (344.5us):
//  - agg64w3: W3 staged as [i*8+f8] rows of 8 fp32 (6 used + 2 pad).
//    Same epilogue structure as R18 (28 VGPR, consecutive-q reads) but rows
//    are 32B-aligned -> float4+float2 vectorized reads, and [i][f8] order
//    puts one instruction's 8 row-addresses at consecutive 32B -> 2-way bank
//    aliasing (free) instead of R18's 4-way conflict (4.8M) or R19's
//    scattered b32 reads (VGPR 40, occupancy 57%).
//  - lin2 reverted to R18 4-tile form (R19's 2-tile change unattributed).
// ---------------------------------------------------------------------------

#define WS_ALIGN(x) (((x) + 255) & ~(size_t)255)
#define BKN 256                 // nodes per bin/sort bucket
#define CAP 9216                // slab capacity per bucket (mean 8184; +11 sigma)
#define EPT 8                   // edges per thread in bin kernel
#define BIN_THR 512
#define BIN_CHUNK (BIN_THR * EPT)  // 4096 edges per WG

typedef _Float16 half8 __attribute__((ext_vector_type(8)));
typedef float floatx4 __attribute__((ext_vector_type(4)));

// ---------------- fat: bin (blocks [0,binG)) || lin1 (blocks [binG,+linG)) ----------------
__global__ __launch_bounds__(512) void fat_bin_lin1_kernel(
    const int* __restrict__ src, const int* __restrict__ dst,
    int* __restrict__ cur, int* __restrict__ slab, int E, int NB, int binG,
    const float* __restrict__ Xf, const float* __restrict__ W1,
    _Float16* __restrict__ Y, int n) {
    __shared__ int smem[5632];   // bin: cnt/incl/gbase[512]x3 + stag[4096] = 22.5KB
    const int tid = threadIdx.x;
    if (blockIdx.x < binG) {
        // ---------------- bin role (round-15 LDS counting sort) ----------------
        int* cnt   = smem;
        int* incl  = smem + 512;
        int* gbase = smem + 1024;
        int* stag  = smem + 1536;
        const int base = blockIdx.x * BIN_CHUNK + tid * EPT;
        cnt[tid] = 0;
        __syncthreads();
        int b[EPT], w[EPT], lp[EPT];
        #pragma unroll
        for (int k = 0; k < EPT; ++k) {
            int e = base + k;
            if (e < E) {
                int s = src[e], d = dst[e];
                b[k] = d >> 8;
                w[k] = (s << 8) | (d & 255);
            } else b[k] = -1;
        }
        #pragma unroll
        for (int k = 0; k < EPT; ++k)
            if (b[k] >= 0) lp[k] = atomicAdd(&cnt[b[k]], 1);
        __syncthreads();
        incl[tid] = cnt[tid];
        __syncthreads();
        for (int off = 1; off < 512; off <<= 1) {
            int v = 0;
            if (tid >= off) v = incl[tid - off];
            __syncthreads();
            incl[tid] += v;
            __syncthreads();
        }
        if (tid < NB) {
            int c = cnt[tid];
            gbase[tid] = c ? atomicAdd(&cur[tid], c) : 0;
        }
        #pragma unroll
        for (int k = 0; k < EPT; ++k)
            if (b[k] >= 0) stag[incl[b[k]] - cnt[b[k]] + lp[k]] = w[k];
        __syncthreads();
        const int total = incl[NB - 1];
        for (int idx = tid; idx < total; idx += BIN_THR) {
            int wv = stag[idx];
            int lo = 0, hi = NB - 1;
            while (lo < hi) { int mid = (lo + hi) >> 1; if (incl[mid] > idx) hi = mid; else lo = mid + 1; }
            int excl = incl[lo] - cnt[lo];
            int p = gbase[lo] + (idx - excl);
            if (p < CAP) slab[(size_t)lo * CAP + p] = wv;
        }
    } else {
        // ---------------- lin1 role: Y16 = fp16(X @ W1), UNSCALED ----------------
        constexpr int K = 128, KC = 4;
        _Float16* Bf = (_Float16*)smem;   // 16KB B-fragment staging
        for (int i = tid; i < KC * 4 * 64 * 8; i += 512) {
            int j = i & 7, lane = (i >> 3) & 63, tile = (i >> 9) & 3, kc = i >> 11;
            int k = kc * 32 + ((lane >> 4) << 3) + j;
            int col = tile * 16 + (lane & 15);
            Bf[i] = (_Float16)W1[k * 64 + col];
        }
        __syncthreads();
        const int lane = tid & 63, wid = tid >> 6;   // 8 waves
        const int mrow = lane & 15, quad = lane >> 4;
        const int lblk = blockIdx.x - binG;
        #pragma unroll
        for (int tt = 0; tt < 2; ++tt) {             // 8 waves x 2 groups = 256 nodes
            const int base = lblk * 256 + wid * 32 + tt * 16;
            if (base >= n) continue;
            const int anode = min(base + mrow, n - 1);
            floatx4 acc[4] = {{0, 0, 0, 0}, {0, 0, 0, 0}, {0, 0, 0, 0}, {0, 0, 0, 0}};
            #pragma unroll
            for (int kc = 0; kc < KC; ++kc) {
                float4 xa = *(const float4*)&Xf[(size_t)anode * K + kc * 32 + quad * 8];
                float4 xb = *(const float4*)&Xf[(size_t)anode * K + kc * 32 + quad * 8 + 4];
                half8 a;
                a[0] = (_Float16)xa.x; a[1] = (_Float16)xa.y; a[2] = (_Float16)xa.z; a[3] = (_Float16)xa.w;
                a[4] = (_Float16)xb.x; a[5] = (_Float16)xb.y; a[6] = (_Float16)xb.z; a[7] = (_Float16)xb.w;
                #pragma unroll
                for (int t = 0; t < 4; ++t) {
                    half8 b = *(const half8*)&Bf[((kc * 4 + t) * 64 + lane) * 8];
                    acc[t] = __builtin_amdgcn_mfma_f32_16x16x32_f16(a, b, acc[t], 0, 0, 0);
                }
            }
            #pragma unroll
            for (int r = 0; r < 4; ++r) {
                int node = base + quad * 4 + r;
                if (node < n) {
                    #pragma unroll
                    for (int t = 0; t < 4; ++t)
                        Y[(size_t)node * 64 + t * 16 + mrow] = (_Float16)acc[t][r];
                }
            }
        }
    }
}

// ---------------- per-bucket counting sort -> per-node CSR + dinv ----------------
__global__ __launch_bounds__(512) void bucket_sort_kernel(
    const int* __restrict__ slab, const int* __restrict__ cur,
    int* __restrict__ srcS, int2* __restrict__ rows,
    float* __restrict__ dinv, int n) {
    __shared__ int cnt[BKN], s[BKN], cursor[BKN];
    const int b = blockIdx.x, tid = threadIdx.x;
    const int m = min(cur[b], CAP);
    const int* sp = slab + (size_t)b * CAP;
    if (tid < BKN) cnt[tid] = 0;
    __syncthreads();
    for (int j = tid; j < m; j += 512) atomicAdd(&cnt[sp[j] & (BKN - 1)], 1);
    __syncthreads();
    if (tid < BKN) s[tid] = cnt[tid];
    __syncthreads();
    for (int off = 1; off < BKN; off <<= 1) {
        int v = 0;
        if (tid < BKN && tid >= off) v = s[tid - off];
        __syncthreads();
        if (tid < BKN) s[tid] += v;
        __syncthreads();
    }
    if (tid < BKN) {
        int ofs = s[tid] - cnt[tid];
        cursor[tid] = ofs;
        int node = b * BKN + tid;
        if (node < n) {
            rows[node] = make_int2(b * CAP + ofs, b * CAP + ofs + cnt[tid]);
            dinv[node] = rsqrtf((float)(cnt[tid] + 1));
        }
    }
    __syncthreads();
    for (int j = tid; j < m; j += 512) {
        int w = sp[j];
        int p = atomicAdd(&cursor[w & (BKN - 1)], 1);
        srcS[(size_t)b * CAP + p] = w >> 8;
    }
}

// ---------------- MFMA linear (fp16 input), K=64, 4 tiles per WG ----------------
__global__ __launch_bounds__(256) void linear_mfma_f16_kernel(
    const _Float16* __restrict__ Xh, const float* __restrict__ W,
    const float* __restrict__ dinv, _Float16* __restrict__ Y, int n) {
    constexpr int K = 64, KC = 2;
    __shared__ _Float16 Bf[KC * 4 * 64 * 8];  // 8KB
    const int tid = threadIdx.x;
    for (int i = tid; i < KC * 4 * 64 * 8; i += 256) {
        int j = i & 7, lane = (i >> 3) & 63, tile = (i >> 9) & 3, kc = i >> 11;
        int k = kc * 32 + ((lane >> 4) << 3) + j;
        int col = tile * 16 + (lane & 15);
        Bf[i] = (_Float16)W[k * 64 + col];
    }
    __syncthreads();
    const int lane = tid & 63, wid = tid >> 6;
    const int mrow = lane & 15, quad = lane >> 4;
    #pragma unroll
    for (int tt = 0; tt < 4; ++tt) {
        const int base = (blockIdx.x * 4 + tt) * 64 + wid * 16;
        if (base >= n) continue;
        const int anode = min(base + mrow, n - 1);
        floatx4 acc[4] = {{0, 0, 0, 0}, {0, 0, 0, 0}, {0, 0, 0, 0}, {0, 0, 0, 0}};
        #pragma unroll
        for (int kc = 0; kc < KC; ++kc) {
            half8 a = *(const half8*)&Xh[(size_t)anode * K + kc * 32 + quad * 8];
            #pragma unroll
            for (int t = 0; t < 4; ++t) {
                half8 b = *(const half8*)&Bf[((kc * 4 + t) * 64 + lane) * 8];
                acc[t] = __builtin_amdgcn_mfma_f32_16x16x32_f16(a, b, acc[t], 0, 0, 0);
            }
        }
        #pragma unroll
        for (int r = 0; r < 4; ++r) {
            int node = base + quad * 4 + r;
            if (node < n) {
                float di = dinv[node];
                #pragma unroll
                for (int t = 0; t < 4; ++t)
                    Y[(size_t)node * 64 + t * 16 + mrow] = (_Float16)(acc[t][r] * di);
            }
        }
    }
}

// ---------------- agg64s (L1): gather UNSCALED h1, scale by dinv[src] in-loop ----------------
// out[i] = relu( (sum_s dinv_s*h1[s] + dinv_i*h1[i]) * dinv_i + b1 )
__global__ __launch_bounds__(256) void agg64s_kernel(
    const _Float16* __restrict__ H1, const float* __restrict__ dinv,
    const int* __restrict__ srcS, const int2* __restrict__ rows,
    const float* __restrict__ bias, _Float16* __restrict__ Out, int n) {
    const int wave = (blockIdx.x * blockDim.x + threadIdx.x) >> 6;
    const int lane = threadIdx.x & 63;
    if (wave >= n) return;
    const int slot = lane >> 3;  // edge slot 0..7
    const int f8 = lane & 7;     // feat slice [f8*8, f8*8+8)
    const int2 row = rows[wave];
    const int beg = row.x, end = row.y;
    half8 hA, hB;
    #pragma unroll
    for (int i = 0; i < 8; ++i) { hA[i] = (_Float16)0.f; hB[i] = (_Float16)0.f; }
    int j = beg;
    for (; j + 32 <= end; j += 32) {      // 32 edges: 4 gathers in flight
        int s0 = srcS[j      + slot];
        int s1 = srcS[j + 8  + slot];
        int s2 = srcS[j + 16 + slot];
        int s3 = srcS[j + 24 + slot];
        _Float16 d0 = (_Float16)dinv[s0];
        _Float16 d1 = (_Float16)dinv[s1];
        _Float16 d2 = (_Float16)dinv[s2];
        _Float16 d3 = (_Float16)dinv[s3];
        half8 v0 = *(const half8*)&H1[(size_t)s0 * 64 + f8 * 8];
        half8 v1 = *(const half8*)&H1[(size_t)s1 * 64 + f8 * 8];
        half8 v2 = *(const half8*)&H1[(size_t)s2 * 64 + f8 * 8];
        half8 v3 = *(const half8*)&H1[(size_t)s3 * 64 + f8 * 8];
        hA += v0 * d0; hB += v1 * d1; hA += v2 * d2; hB += v3 * d3;
    }
    for (; j + 16 <= end; j += 16) {      // 16 edges
        int s0 = srcS[j + slot];
        int s1 = srcS[j + 8 + slot];
        _Float16 d0 = (_Float16)dinv[s0];
        _Float16 d1 = (_Float16)dinv[s1];
        half8 v0 = *(const half8*)&H1[(size_t)s0 * 64 + f8 * 8];
        half8 v1 = *(const half8*)&H1[(size_t)s1 * 64 + f8 * 8];
        hA += v0 * d0; hB += v1 * d1;
    }
    for (; j < end; j += 8) {             // tail (exec-masked)
        int jj = j + slot;
        if (jj < end) {
            int s0 = srcS[jj];
            _Float16 d0 = (_Float16)dinv[s0];
            half8 v = *(const half8*)&H1[(size_t)s0 * 64 + f8 * 8];
            hA += v * d0;
        }
    }
    half8 ht = hA + hB;
    #pragma unroll
    for (int mask = 8; mask <= 32; mask <<= 1) {  // packed fold over slots
        int4 ci = *(int4*)&ht, oi;
        oi.x = __shfl_xor(ci.x, mask);
        oi.y = __shfl_xor(ci.y, mask);
        oi.z = __shfl_xor(ci.z, mask);
        oi.w = __shfl_xor(ci.w, mask);
        ht += *(half8*)&oi;
    }
    half8 self = *(const half8*)&H1[(size_t)wave * 64 + f8 * 8];
    const float di = dinv[wave];
    float4 b0 = *(const float4*)&bias[f8 * 8];
    float4 b1v = *(const float4*)&bias[f8 * 8 + 4];
    float bb[8] = {b0.x, b0.y, b0.z, b0.w, b1v.x, b1v.y, b1v.z, b1v.w};
    half8 o;
    #pragma unroll
    for (int i = 0; i < 8; ++i) {
        float t = ((float)ht[i] + di * (float)self[i]) * di + bb[i];
        o[i] = (_Float16)fmaxf(t, 0.f);
    }
    if (slot == 0) *(half8*)&Out[(size_t)wave * 64 + f8 * 8] = o;
}

// ---------------- agg64w3 (L2): aggregate Hs2 + relu -> h2, project W3, write hsC ----------------
// h2[f] = relu( (sum_s Hs2[s] + Hs2[i]) * di + b2[f] );  hsC[i][q] = di * sum_f h2[f] W3[f][q]
// W3 staged as [i*8+f8] rows of 8 fp32 (6+2 pad): aligned float4+float2 reads,
// [i][f8] order -> one instruction's 8 rows at consecutive 32B -> 2-way (free).
__global__ __launch_bounds__(256) void agg64w3_kernel(
    const _Float16* __restrict__ Hs, const float* __restrict__ dinv,
    const int* __restrict__ srcS, const int2* __restrict__ rows,
    const float* __restrict__ bias, const float* __restrict__ W3,
    __half* __restrict__ Yc, int n) {
    __shared__ float W3p[64 * 8];   // 2KB: W3p[(i*8+f8)*8 + q] = W3[(f8*8+i)*6 + q]
    const int tid = threadIdx.x;
    for (int idx = tid; idx < 64 * 8; idx += 256) {
        int rowi = idx >> 3, q = idx & 7;
        int i = rowi >> 3, f8v = rowi & 7;
        W3p[idx] = (q < 6) ? W3[(f8v * 8 + i) * 6 + q] : 0.f;
    }
    __syncthreads();
    const int wave = (blockIdx.x * blockDim.x + tid) >> 6;
    const int lane = tid & 63;
    if (wave >= n) return;
    const int slot = lane >> 3;
    const int f8 = lane & 7;
    const int2 row = rows[wave];
    const int beg = row.x, end = row.y;
    half8 hA, hB;
    #pragma unroll
    for (int i = 0; i < 8; ++i) { hA[i] = (_Float16)0.f; hB[i] = (_Float16)0.f; }
    int j = beg;
    for (; j + 32 <= end; j += 32) {
        int s0 = srcS[j      + slot];
        int s1 = srcS[j + 8  + slot];
        int s2 = srcS[j + 16 + slot];
        int s3 = srcS[j + 24 + slot];
        half8 v0 = *(const half8*)&Hs[(size_t)s0 * 64 + f8 * 8];
        half8 v1 = *(const half8*)&Hs[(size_t)s1 * 64 + f8 * 8];
        half8 v2 = *(const half8*)&Hs[(size_t)s2 * 64 + f8 * 8];
        half8 v3 = *(const half8*)&Hs[(size_t)s3 * 64 + f8 * 8];
        hA += v0; hB += v1; hA += v2; hB += v3;
    }
    for (; j + 16 <= end; j += 16) {
        int s0 = srcS[j + slot];
        int s1 = srcS[j + 8 + slot];
        half8 v0 = *(const half8*)&Hs[(size_t)s0 * 64 + f8 * 8];
        half8 v1 = *(const half8*)&Hs[(size_t)s1 * 64 + f8 * 8];
        hA += v0; hB += v1;
    }
    for (; j < end; j += 8) {
        int jj = j + slot;
        if (jj < end) {
            half8 v = *(const half8*)&Hs[(size_t)srcS[jj] * 64 + f8 * 8];
            hA += v;
        }
    }
    half8 ht = hA + hB;
    #pragma unroll
    for (int mask = 8; mask <= 32; mask <<= 1) {
        int4 ci = *(int4*)&ht, oi;
        oi.x = __shfl_xor(ci.x, mask);
        oi.y = __shfl_xor(ci.y, mask);
        oi.z = __shfl_xor(ci.z, mask);
        oi.w = __shfl_xor(ci.w, mask);
        ht += *(half8*)&oi;
    }
    half8 self = *(const half8*)&Hs[(size_t)wave * 64 + f8 * 8];
    const float di = dinv[wave];
    float4 b0 = *(const float4*)&bias[f8 * 8];
    float4 b1v = *(const float4*)&bias[f8 * 8 + 4];
    float bb[8] = {b0.x, b0.y, b0.z, b0.w, b1v.x, b1v.y, b1v.z, b1v.w};
    // h2 for this lane's 8 feats, then W3 partial projection (aligned rows)
    float p[6] = {0.f, 0.f, 0.f, 0.f, 0.f, 0.f};
    #pragma unroll
    for (int i = 0; i < 8; ++i) {
        float h2 = fmaxf(((float)ht[i] + (float)self[i]) * di + bb[i], 0.f);
        const float* wr = &W3p[(i * 8 + f8) * 8];
        float4 w0 = *(const float4*)wr;
        float2 w1 = *(const float2*)(wr + 4);
        p[0] = fmaf(h2, w0.x, p[0]);
        p[1] = fmaf(h2, w0.y, p[1]);
        p[2] = fmaf(h2, w0.z, p[2]);
        p[3] = fmaf(h2, w0.w, p[3]);
        p[4] = fmaf(h2, w1.x, p[4]);
        p[5] = fmaf(h2, w1.y, p[5]);
    }
    #pragma unroll
    for (int mask = 1; mask <= 4; mask <<= 1) {   // fold over f8 (bits 0..2)
        #pragma unroll
        for (int q = 0; q < 6; ++q) p[q] += __shfl_xor(p[q], mask);
    }
    if (lane == 0) {
        half8 o;
        #pragma unroll
        for (int q = 0; q < 6; ++q) o[q] = (_Float16)(p[q] * di);
        o[6] = (_Float16)0.f; o[7] = (_Float16)0.f;
        *(half8*)&Yc[(size_t)wave * 8] = o;
    }
}

// ---------------- aggregate 6 feats + bias + log_softmax: lane-per-edge ----------------
__global__ __launch_bounds__(256) void agg6_lsm_kernel(
    const _Float16* __restrict__ Hs6, const float* __restrict__ dinv,
    const int* __restrict__ srcS, const int2* __restrict__ rows,
    const float* __restrict__ bias, float* __restrict__ out, int n) {
    const int wave = (blockIdx.x * blockDim.x + threadIdx.x) >> 6;
    const int lane = threadIdx.x & 63;
    if (wave >= n) return;
    const int2 row = rows[wave];
    const int beg = row.x, end = row.y;
    half8 ht;
    #pragma unroll
    for (int i = 0; i < 8; ++i) ht[i] = (_Float16)0.f;
    for (int j = beg + lane; j < end; j += 64) {          // 1 iter typ. (deg~32)
        int s = srcS[j];
        ht += *(const half8*)&Hs6[(size_t)s * 8];          // 16B row gather
    }
    #pragma unroll
    for (int mask = 1; mask <= 32; mask <<= 1) {          // packed fold, 64 lanes
        int4 ci = *(int4*)&ht, oi;
        oi.x = __shfl_xor(ci.x, mask);
        oi.y = __shfl_xor(ci.y, mask);
        oi.z = __shfl_xor(ci.z, mask);
        oi.w = __shfl_xor(ci.w, mask);
        ht += *(half8*)&oi;
    }
    half8 self = *(const half8*)&Hs6[(size_t)wave * 8];
    const float di = dinv[wave];
    float a[6];
    #pragma unroll
    for (int q = 0; q < 6; ++q)
        a[q] = ((float)ht[q] + (float)self[q]) * di + bias[q];
    float mx = a[0];
    #pragma unroll
    for (int q = 1; q < 6; ++q) mx = fmaxf(mx, a[q]);
    float sum = 0.f;
    #pragma unroll
    for (int q = 0; q < 6; ++q) sum += expf(a[q] - mx);
    float lse = mx + logf(sum);
    if (lane == 0) {
        float* op = &out[(size_t)wave * 6];
        *(float2*)(op)     = make_float2(a[0] - lse, a[1] - lse);
        *(float2*)(op + 2) = make_float2(a[2] - lse, a[3] - lse);
        *(float2*)(op + 4) = make_float2(a[4] - lse, a[5] - lse);
    }
}

// ---------------------------------------------------------------------------
extern "C" void kernel_launch(void* const* d_in, const int* in_sizes, int n_in,
                              void* d_out, int out_size, void* d_ws, size_t ws_size,
                              hipStream_t stream) {
    const float* x  = (const float*)d_in[0];
    const int*   ei = (const int*)d_in[1];
    const float* W1 = (const float*)d_in[2];
    const float* b1 = (const float*)d_in[3];
    const float* W2 = (const float*)d_in[4];
    const float* b2 = (const float*)d_in[5];
    const float* W3 = (const float*)d_in[6];
    const float* b3 = (const float*)d_in[7];
    float* out = (float*)d_out;

    const int n = in_sizes[0] / 128;  // 100000
    const int E = in_sizes[1] / 2;    // 3200000
    const int* src = ei;
    const int* dst = ei + E;
    const int NB = (n + BKN - 1) / BKN;  // 391

    // ---- workspace carve ----
    char* ws = (char*)d_ws;
    auto carve = [&](size_t bytes) { char* p = ws; ws += WS_ALIGN(bytes); return p; };
    int*      cur  = (int*)     carve((size_t)NB * 4);
    float*    dinv = (float*)   carve((size_t)n * 4);
    int*      slab = (int*)     carve((size_t)NB * CAP * 4);   // 14.4 MB
    int*      srcS = (int*)     carve((size_t)NB * CAP * 4);   // 14.4 MB
    int2*     rows = (int2*)    carve((size_t)n * 8);
    _Float16* hsA  = (_Float16*)carve((size_t)n * 64 * 2 + 4096);   // 12.8 MB
    _Float16* hsB  = (_Float16*)carve((size_t)n * 64 * 2 + 4096);   // 12.8 MB
    _Float16* hsC  = (_Float16*)carve((size_t)n * 8 * 2);           // 1.6 MB
    (void)ws_size; (void)n_in; (void)out_size;

    const int binG = (E + BIN_CHUNK - 1) / BIN_CHUNK;   // 782
    const int linG = (n + 255) / 256;                   // 391
    const int aggGrid = (n + 3) / 4;

    // ---- CSR phase 1 || layer-1 linear (independent after dinv decoupling) ----
    (void)hipMemsetAsync(cur, 0, (size_t)NB * 4, stream);
    fat_bin_lin1_kernel<<<binG + linG, 512, 0, stream>>>(
        src, dst, cur, slab, E, NB, binG, x, W1, hsA, n);

    // ---- CSR phase 2 ----
    bucket_sort_kernel<<<NB, 512, 0, stream>>>(slab, cur, srcS, rows, dinv, n);

    // ---- layer 1 aggregation (dinv[src] applied in-loop) ----
    agg64s_kernel<<<aggGrid, 256, 0, stream>>>(hsA, dinv, srcS, rows, b1, hsB, n);

    // ---- layer 2 linear ----
    linear_mfma_f16_kernel<<<(n + 255) / 256, 256, 0, stream>>>(hsB, W2, dinv, hsA, n);

    // ---- layer 2 aggregation + fused W3 projection ----
    agg64w3_kernel<<<aggGrid, 256, 0, stream>>>(hsA, dinv, srcS, rows, b2, W3, (__half*)hsC, n);

    // ---- layer 3 aggregation + log_softmax ----
    agg6_lsm_kernel<<<aggGrid, 256, 0, stream>>>(hsC, dinv, srcS, rows, b3, out, n);
}

// Round 11
// 347.910 us; speedup vs baseline: 1.0211x; 1.0075x over previous
//
#include <hip/hip_runtime.h>
#include <hip/hip_fp16.h>
#include <math.h>

// ---------------------------------------------------------------------------
// GCN 3-layer forward, round 21 (= round 18 + low-sync CSR build).
// out[i] = dinv[i] * ( sum_{e:dst=i} Hs[src] + Hs[i] ) + b,  Hs = (X@W)*dinv.
// Round-21 delta vs round-18 (344.5us, best verified):
//  - bin (fat role): 512-wide Hillis-Steele scan (18 barriers) -> per-wave
//    __shfl_up scan + cross-wave combine (2 barriers).
//  - bucket_sort: per-wave private histograms cnt8[8][256] (LDS atomics
//    contend only within a wave, 8x less serialization in count AND scatter),
//    thread-t combine -> per-wave exclusive bases, shfl scan for the 256-wide
//    prefix (4 barriers vs ~20). Output byte-equivalent CSR.
//  - agg64w3: R18 byte-exact form (74us; R19/R20 proved its LDS conflicts
//    are hidden under gather latency -- occupancy is what matters).
// ---------------------------------------------------------------------------

#define WS_ALIGN(x) (((x) + 255) & ~(size_t)255)
#define BKN 256                 // nodes per bin/sort bucket
#define CAP 9216                // slab capacity per bucket (mean 8184; +11 sigma)
#define EPT 8                   // edges per thread in bin kernel
#define BIN_THR 512
#define BIN_CHUNK (BIN_THR * EPT)  // 4096 edges per WG

typedef _Float16 half8 __attribute__((ext_vector_type(8)));
typedef float floatx4 __attribute__((ext_vector_type(4)));

// ---------------- fat: bin (blocks [0,binG)) || lin1 (blocks [binG,+linG)) ----------------
__global__ __launch_bounds__(512) void fat_bin_lin1_kernel(
    const int* __restrict__ src, const int* __restrict__ dst,
    int* __restrict__ cur, int* __restrict__ slab, int E, int NB, int binG,
    const float* __restrict__ Xf, const float* __restrict__ W1,
    _Float16* __restrict__ Y, int n) {
    __shared__ int smem[5632];   // bin: cnt/incl/gbase[512]x3 + stag[4096] = 22.5KB
    __shared__ int wtot8[8];
    const int tid = threadIdx.x;
    if (blockIdx.x < binG) {
        // ---------------- bin role: LDS counting sort, shfl scan ----------------
        int* cnt   = smem;
        int* incl  = smem + 512;
        int* gbase = smem + 1024;
        int* stag  = smem + 1536;
        const int lane = tid & 63, wv = tid >> 6;
        const int base = blockIdx.x * BIN_CHUNK + tid * EPT;
        cnt[tid] = 0;
        __syncthreads();
        int b[EPT], w[EPT], lp[EPT];
        #pragma unroll
        for (int k = 0; k < EPT; ++k) {
            int e = base + k;
            if (e < E) {
                int s = src[e], d = dst[e];
                b[k] = d >> 8;
                w[k] = (s << 8) | (d & 255);
            } else b[k] = -1;
        }
        #pragma unroll
        for (int k = 0; k < EPT; ++k)
            if (b[k] >= 0) lp[k] = atomicAdd(&cnt[b[k]], 1);
        __syncthreads();
        // inclusive scan over 512 counters: per-wave shfl + cross-wave combine
        int x = cnt[tid];
        #pragma unroll
        for (int off = 1; off < 64; off <<= 1) {
            int y = __shfl_up(x, off);
            if (lane >= off) x += y;
        }
        if (lane == 63) wtot8[wv] = x;
        __syncthreads();
        int add = 0;
        #pragma unroll
        for (int ww = 0; ww < 8; ++ww) add += (ww < wv) ? wtot8[ww] : 0;
        incl[tid] = x + add;
        if (tid < NB) {
            int c = cnt[tid];
            gbase[tid] = c ? atomicAdd(&cur[tid], c) : 0;
        }
        __syncthreads();
        // stage sorted-by-bucket into LDS
        #pragma unroll
        for (int k = 0; k < EPT; ++k)
            if (b[k] >= 0) stag[incl[b[k]] - cnt[b[k]] + lp[k]] = w[k];
        __syncthreads();
        const int total = incl[NB - 1];
        // burst write: consecutive lanes -> consecutive slots of the same run
        for (int idx = tid; idx < total; idx += BIN_THR) {
            int wv2 = stag[idx];
            int lo = 0, hi = NB - 1;
            while (lo < hi) { int mid = (lo + hi) >> 1; if (incl[mid] > idx) hi = mid; else lo = mid + 1; }
            int excl = incl[lo] - cnt[lo];
            int p = gbase[lo] + (idx - excl);
            if (p < CAP) slab[(size_t)lo * CAP + p] = wv2;
        }
    } else {
        // ---------------- lin1 role: Y16 = fp16(X @ W1), UNSCALED ----------------
        constexpr int K = 128, KC = 4;
        _Float16* Bf = (_Float16*)smem;   // 16KB B-fragment staging
        for (int i = tid; i < KC * 4 * 64 * 8; i += 512) {
            int j = i & 7, lane = (i >> 3) & 63, tile = (i >> 9) & 3, kc = i >> 11;
            int k = kc * 32 + ((lane >> 4) << 3) + j;
            int col = tile * 16 + (lane & 15);
            Bf[i] = (_Float16)W1[k * 64 + col];
        }
        __syncthreads();
        const int lane = tid & 63, wid = tid >> 6;   // 8 waves
        const int mrow = lane & 15, quad = lane >> 4;
        const int lblk = blockIdx.x - binG;
        #pragma unroll
        for (int tt = 0; tt < 2; ++tt) {             // 8 waves x 2 groups = 256 nodes
            const int base = lblk * 256 + wid * 32 + tt * 16;
            if (base >= n) continue;
            const int anode = min(base + mrow, n - 1);
            floatx4 acc[4] = {{0, 0, 0, 0}, {0, 0, 0, 0}, {0, 0, 0, 0}, {0, 0, 0, 0}};
            #pragma unroll
            for (int kc = 0; kc < KC; ++kc) {
                float4 xa = *(const float4*)&Xf[(size_t)anode * K + kc * 32 + quad * 8];
                float4 xb = *(const float4*)&Xf[(size_t)anode * K + kc * 32 + quad * 8 + 4];
                half8 a;
                a[0] = (_Float16)xa.x; a[1] = (_Float16)xa.y; a[2] = (_Float16)xa.z; a[3] = (_Float16)xa.w;
                a[4] = (_Float16)xb.x; a[5] = (_Float16)xb.y; a[6] = (_Float16)xb.z; a[7] = (_Float16)xb.w;
                #pragma unroll
                for (int t = 0; t < 4; ++t) {
                    half8 b = *(const half8*)&Bf[((kc * 4 + t) * 64 + lane) * 8];
                    acc[t] = __builtin_amdgcn_mfma_f32_16x16x32_f16(a, b, acc[t], 0, 0, 0);
                }
            }
            #pragma unroll
            for (int r = 0; r < 4; ++r) {
                int node = base + quad * 4 + r;
                if (node < n) {
                    #pragma unroll
                    for (int t = 0; t < 4; ++t)
                        Y[(size_t)node * 64 + t * 16 + mrow] = (_Float16)acc[t][r];
                }
            }
        }
    }
}

// ---------------- bucket_sort: per-wave private histograms, low-sync ----------------
__global__ __launch_bounds__(512) void bucket_sort_kernel(
    const int* __restrict__ slab, const int* __restrict__ cur,
    int* __restrict__ srcS, int2* __restrict__ rows,
    float* __restrict__ dinv, int n) {
    __shared__ int cnt8[8][BKN];   // 8KB private histograms / per-wave bases
    __shared__ int tot[BKN];       // node degree -> local start
    __shared__ int wtot[4];
    const int b = blockIdx.x, tid = threadIdx.x;
    const int lane = tid & 63, wv = tid >> 6;
    const int m = min(cur[b], CAP);
    const int* sp = slab + (size_t)b * CAP;
    for (int i = tid; i < 8 * BKN; i += 512) ((int*)cnt8)[i] = 0;
    __syncthreads();
    // count: within-wave contention only
    for (int j = tid; j < m; j += 512) atomicAdd(&cnt8[wv][sp[j] & (BKN - 1)], 1);
    __syncthreads();
    // combine: per-node total + per-wave exclusive bases (in place)
    if (tid < BKN) {
        int run = 0;
        #pragma unroll
        for (int w = 0; w < 8; ++w) { int c = cnt8[w][tid]; cnt8[w][tid] = run; run += c; }
        tot[tid] = run;
    }
    __syncthreads();
    // inclusive scan of tot[0..255]: per-wave shfl + combine (4 waves)
    int x = 0;
    if (tid < BKN) {
        x = tot[tid];
        #pragma unroll
        for (int off = 1; off < 64; off <<= 1) {
            int y = __shfl_up(x, off);
            if (lane >= off) x += y;
        }
        if (lane == 63) wtot[wv] = x;
    }
    __syncthreads();
    if (tid < BKN) {
        int add = 0;
        #pragma unroll
        for (int w = 0; w < 4; ++w) add += (w < wv) ? wtot[w] : 0;
        const int d = tot[tid];
        const int start = x + add - d;    // exclusive prefix
        tot[tid] = start;                  // reuse as local start
        const int node = b * BKN + tid;
        if (node < n) {
            rows[node] = make_int2(b * CAP + start, b * CAP + start + d);
            dinv[node] = rsqrtf((float)(d + 1));
        }
    }
    __syncthreads();
    // scatter: pos = start[node] + (per-wave base ++) ; within-wave atomics only
    for (int j = tid; j < m; j += 512) {
        int w = sp[j];
        int node = w & (BKN - 1);
        int p = tot[node] + atomicAdd(&cnt8[wv][node], 1);
        srcS[(size_t)b * CAP + p] = w >> 8;
    }
}

// ---------------- MFMA linear (fp16 input), K=64, 4 tiles per WG ----------------
__global__ __launch_bounds__(256) void linear_mfma_f16_kernel(
    const _Float16* __restrict__ Xh, const float* __restrict__ W,
    const float* __restrict__ dinv, _Float16* __restrict__ Y, int n) {
    constexpr int K = 64, KC = 2;
    __shared__ _Float16 Bf[KC * 4 * 64 * 8];  // 8KB
    const int tid = threadIdx.x;
    for (int i = tid; i < KC * 4 * 64 * 8; i += 256) {
        int j = i & 7, lane = (i >> 3) & 63, tile = (i >> 9) & 3, kc = i >> 11;
        int k = kc * 32 + ((lane >> 4) << 3) + j;
        int col = tile * 16 + (lane & 15);
        Bf[i] = (_Float16)W[k * 64 + col];
    }
    __syncthreads();
    const int lane = tid & 63, wid = tid >> 6;
    const int mrow = lane & 15, quad = lane >> 4;
    #pragma unroll
    for (int tt = 0; tt < 4; ++tt) {
        const int base = (blockIdx.x * 4 + tt) * 64 + wid * 16;
        if (base >= n) continue;
        const int anode = min(base + mrow, n - 1);
        floatx4 acc[4] = {{0, 0, 0, 0}, {0, 0, 0, 0}, {0, 0, 0, 0}, {0, 0, 0, 0}};
        #pragma unroll
        for (int kc = 0; kc < KC; ++kc) {
            half8 a = *(const half8*)&Xh[(size_t)anode * K + kc * 32 + quad * 8];
            #pragma unroll
            for (int t = 0; t < 4; ++t) {
                half8 b = *(const half8*)&Bf[((kc * 4 + t) * 64 + lane) * 8];
                acc[t] = __builtin_amdgcn_mfma_f32_16x16x32_f16(a, b, acc[t], 0, 0, 0);
            }
        }
        #pragma unroll
        for (int r = 0; r < 4; ++r) {
            int node = base + quad * 4 + r;
            if (node < n) {
                float di = dinv[node];
                #pragma unroll
                for (int t = 0; t < 4; ++t)
                    Y[(size_t)node * 64 + t * 16 + mrow] = (_Float16)(acc[t][r] * di);
            }
        }
    }
}

// ---------------- agg64s (L1): gather UNSCALED h1, scale by dinv[src] in-loop ----------------
// out[i] = relu( (sum_s dinv_s*h1[s] + dinv_i*h1[i]) * dinv_i + b1 )
__global__ __launch_bounds__(256) void agg64s_kernel(
    const _Float16* __restrict__ H1, const float* __restrict__ dinv,
    const int* __restrict__ srcS, const int2* __restrict__ rows,
    const float* __restrict__ bias, _Float16* __restrict__ Out, int n) {
    const int wave = (blockIdx.x * blockDim.x + threadIdx.x) >> 6;
    const int lane = threadIdx.x & 63;
    if (wave >= n) return;
    const int slot = lane >> 3;  // edge slot 0..7
    const int f8 = lane & 7;     // feat slice [f8*8, f8*8+8)
    const int2 row = rows[wave];
    const int beg = row.x, end = row.y;
    half8 hA, hB;
    #pragma unroll
    for (int i = 0; i < 8; ++i) { hA[i] = (_Float16)0.f; hB[i] = (_Float16)0.f; }
    int j = beg;
    for (; j + 32 <= end; j += 32) {      // 32 edges: 4 gathers in flight
        int s0 = srcS[j      + slot];
        int s1 = srcS[j + 8  + slot];
        int s2 = srcS[j + 16 + slot];
        int s3 = srcS[j + 24 + slot];
        _Float16 d0 = (_Float16)dinv[s0];
        _Float16 d1 = (_Float16)dinv[s1];
        _Float16 d2 = (_Float16)dinv[s2];
        _Float16 d3 = (_Float16)dinv[s3];
        half8 v0 = *(const half8*)&H1[(size_t)s0 * 64 + f8 * 8];
        half8 v1 = *(const half8*)&H1[(size_t)s1 * 64 + f8 * 8];
        half8 v2 = *(const half8*)&H1[(size_t)s2 * 64 + f8 * 8];
        half8 v3 = *(const half8*)&H1[(size_t)s3 * 64 + f8 * 8];
        hA += v0 * d0; hB += v1 * d1; hA += v2 * d2; hB += v3 * d3;
    }
    for (; j + 16 <= end; j += 16) {      // 16 edges
        int s0 = srcS[j + slot];
        int s1 = srcS[j + 8 + slot];
        _Float16 d0 = (_Float16)dinv[s0];
        _Float16 d1 = (_Float16)dinv[s1];
        half8 v0 = *(const half8*)&H1[(size_t)s0 * 64 + f8 * 8];
        half8 v1 = *(const half8*)&H1[(size_t)s1 * 64 + f8 * 8];
        hA += v0 * d0; hB += v1 * d1;
    }
    for (; j < end; j += 8) {             // tail (exec-masked)
        int jj = j + slot;
        if (jj < end) {
            int s0 = srcS[jj];
            _Float16 d0 = (_Float16)dinv[s0];
            half8 v = *(const half8*)&H1[(size_t)s0 * 64 + f8 * 8];
            hA += v * d0;
        }
    }
    half8 ht = hA + hB;
    #pragma unroll
    for (int mask = 8; mask <= 32; mask <<= 1) {  // packed fold over slots
        int4 ci = *(int4*)&ht, oi;
        oi.x = __shfl_xor(ci.x, mask);
        oi.y = __shfl_xor(ci.y, mask);
        oi.z = __shfl_xor(ci.z, mask);
        oi.w = __shfl_xor(ci.w, mask);
        ht += *(half8*)&oi;
    }
    half8 self = *(const half8*)&H1[(size_t)wave * 64 + f8 * 8];
    const float di = dinv[wave];
    float4 b0 = *(const float4*)&bias[f8 * 8];
    float4 b1v = *(const float4*)&bias[f8 * 8 + 4];
    float bb[8] = {b0.x, b0.y, b0.z, b0.w, b1v.x, b1v.y, b1v.z, b1v.w};
    half8 o;
    #pragma unroll
    for (int i = 0; i < 8; ++i) {
        float t = ((float)ht[i] + di * (float)self[i]) * di + bb[i];
        o[i] = (_Float16)fmaxf(t, 0.f);
    }
    if (slot == 0) *(half8*)&Out[(size_t)wave * 64 + f8 * 8] = o;
}

// ---------------- agg64w3 (L2): aggregate Hs2 + relu -> h2, project W3, write hsC ----------------
// h2[f] = relu( (sum_s Hs2[s] + Hs2[i]) * di + b2[f] );  hsC[i][q] = di * sum_f h2[f] W3[f][q]
// R18 byte-exact form (conflicts hidden under gather latency; occupancy rules).
__global__ __launch_bounds__(256) void agg64w3_kernel(
    const _Float16* __restrict__ Hs, const float* __restrict__ dinv,
    const int* __restrict__ srcS, const int2* __restrict__ rows,
    const float* __restrict__ bias, const float* __restrict__ W3,
    __half* __restrict__ Yc, int n) {
    __shared__ float W3l[64 * 6];
    const int tid = threadIdx.x;
    for (int i = tid; i < 64 * 6; i += 256) W3l[i] = W3[i];
    __syncthreads();
    const int wave = (blockIdx.x * blockDim.x + tid) >> 6;
    const int lane = tid & 63;
    if (wave >= n) return;
    const int slot = lane >> 3;
    const int f8 = lane & 7;
    const int2 row = rows[wave];
    const int beg = row.x, end = row.y;
    half8 hA, hB;
    #pragma unroll
    for (int i = 0; i < 8; ++i) { hA[i] = (_Float16)0.f; hB[i] = (_Float16)0.f; }
    int j = beg;
    for (; j + 32 <= end; j += 32) {
        int s0 = srcS[j      + slot];
        int s1 = srcS[j + 8  + slot];
        int s2 = srcS[j + 16 + slot];
        int s3 = srcS[j + 24 + slot];
        half8 v0 = *(const half8*)&Hs[(size_t)s0 * 64 + f8 * 8];
        half8 v1 = *(const half8*)&Hs[(size_t)s1 * 64 + f8 * 8];
        half8 v2 = *(const half8*)&Hs[(size_t)s2 * 64 + f8 * 8];
        half8 v3 = *(const half8*)&Hs[(size_t)s3 * 64 + f8 * 8];
        hA += v0; hB += v1; hA += v2; hB += v3;
    }
    for (; j + 16 <= end; j += 16) {
        int s0 = srcS[j + slot];
        int s1 = srcS[j + 8 + slot];
        half8 v0 = *(const half8*)&Hs[(size_t)s0 * 64 + f8 * 8];
        half8 v1 = *(const half8*)&Hs[(size_t)s1 * 64 + f8 * 8];
        hA += v0; hB += v1;
    }
    for (; j < end; j += 8) {
        int jj = j + slot;
        if (jj < end) {
            half8 v = *(const half8*)&Hs[(size_t)srcS[jj] * 64 + f8 * 8];
            hA += v;
        }
    }
    half8 ht = hA + hB;
    #pragma unroll
    for (int mask = 8; mask <= 32; mask <<= 1) {
        int4 ci = *(int4*)&ht, oi;
        oi.x = __shfl_xor(ci.x, mask);
        oi.y = __shfl_xor(ci.y, mask);
        oi.z = __shfl_xor(ci.z, mask);
        oi.w = __shfl_xor(ci.w, mask);
        ht += *(half8*)&oi;
    }
    half8 self = *(const half8*)&Hs[(size_t)wave * 64 + f8 * 8];
    const float di = dinv[wave];
    float4 b0 = *(const float4*)&bias[f8 * 8];
    float4 b1v = *(const float4*)&bias[f8 * 8 + 4];
    float bb[8] = {b0.x, b0.y, b0.z, b0.w, b1v.x, b1v.y, b1v.z, b1v.w};
    // h2 for this lane's 8 feats, then W3 partial projection
    float p[6] = {0.f, 0.f, 0.f, 0.f, 0.f, 0.f};
    #pragma unroll
    for (int i = 0; i < 8; ++i) {
        float h2 = fmaxf(((float)ht[i] + (float)self[i]) * di + bb[i], 0.f);
        const float* wr = &W3l[(f8 * 8 + i) * 6];
        #pragma unroll
        for (int q = 0; q < 6; ++q) p[q] = fmaf(h2, wr[q], p[q]);
    }
    #pragma unroll
    for (int mask = 1; mask <= 4; mask <<= 1) {   // fold over f8 (bits 0..2)
        #pragma unroll
        for (int q = 0; q < 6; ++q) p[q] += __shfl_xor(p[q], mask);
    }
    if (lane == 0) {
        half8 o;
        #pragma unroll
        for (int q = 0; q < 6; ++q) o[q] = (_Float16)(p[q] * di);
        o[6] = (_Float16)0.f; o[7] = (_Float16)0.f;
        *(half8*)&Yc[(size_t)wave * 8] = o;
    }
}

// ---------------- aggregate 6 feats + bias + log_softmax: lane-per-edge ----------------
__global__ __launch_bounds__(256) void agg6_lsm_kernel(
    const _Float16* __restrict__ Hs6, const float* __restrict__ dinv,
    const int* __restrict__ srcS, const int2* __restrict__ rows,
    const float* __restrict__ bias, float* __restrict__ out, int n) {
    const int wave = (blockIdx.x * blockDim.x + threadIdx.x) >> 6;
    const int lane = threadIdx.x & 63;
    if (wave >= n) return;
    const int2 row = rows[wave];
    const int beg = row.x, end = row.y;
    half8 ht;
    #pragma unroll
    for (int i = 0; i < 8; ++i) ht[i] = (_Float16)0.f;
    for (int j = beg + lane; j < end; j += 64) {          // 1 iter typ. (deg~32)
        int s = srcS[j];
        ht += *(const half8*)&Hs6[(size_t)s * 8];          // 16B row gather
    }
    #pragma unroll
    for (int mask = 1; mask <= 32; mask <<= 1) {          // packed fold, 64 lanes
        int4 ci = *(int4*)&ht, oi;
        oi.x = __shfl_xor(ci.x, mask);
        oi.y = __shfl_xor(ci.y, mask);
        oi.z = __shfl_xor(ci.z, mask);
        oi.w = __shfl_xor(ci.w, mask);
        ht += *(half8*)&oi;
    }
    half8 self = *(const half8*)&Hs6[(size_t)wave * 8];
    const float di = dinv[wave];
    float a[6];
    #pragma unroll
    for (int q = 0; q < 6; ++q)
        a[q] = ((float)ht[q] + (float)self[q]) * di + bias[q];
    float mx = a[0];
    #pragma unroll
    for (int q = 1; q < 6; ++q) mx = fmaxf(mx, a[q]);
    float sum = 0.f;
    #pragma unroll
    for (int q = 0; q < 6; ++q) sum += expf(a[q] - mx);
    float lse = mx + logf(sum);
    if (lane == 0) {
        float* op = &out[(size_t)wave * 6];
        *(float2*)(op)     = make_float2(a[0] - lse, a[1] - lse);
        *(float2*)(op + 2) = make_float2(a[2] - lse, a[3] - lse);
        *(float2*)(op + 4) = make_float2(a[4] - lse, a[5] - lse);
    }
}

// ---------------------------------------------------------------------------
extern "C" void kernel_launch(void* const* d_in, const int* in_sizes, int n_in,
                              void* d_out, int out_size, void* d_ws, size_t ws_size,
                              hipStream_t stream) {
    const float* x  = (const float*)d_in[0];
    const int*   ei = (const int*)d_in[1];
    const float* W1 = (const float*)d_in[2];
    const float* b1 = (const float*)d_in[3];
    const float* W2 = (const float*)d_in[4];
    const float* b2 = (const float*)d_in[5];
    const float* W3 = (const float*)d_in[6];
    const float* b3 = (const float*)d_in[7];
    float* out = (float*)d_out;

    const int n = in_sizes[0] / 128;  // 100000
    const int E = in_sizes[1] / 2;    // 3200000
    const int* src = ei;
    const int* dst = ei + E;
    const int NB = (n + BKN - 1) / BKN;  // 391

    // ---- workspace carve ----
    char* ws = (char*)d_ws;
    auto carve = [&](size_t bytes) { char* p = ws; ws += WS_ALIGN(bytes); return p; };
    int*      cur  = (int*)     carve((size_t)NB * 4);
    float*    dinv = (float*)   carve((size_t)n * 4);
    int*      slab = (int*)     carve((size_t)NB * CAP * 4);   // 14.4 MB
    int*      srcS = (int*)     carve((size_t)NB * CAP * 4);   // 14.4 MB
    int2*     rows = (int2*)    carve((size_t)n * 8);
    _Float16* hsA  = (_Float16*)carve((size_t)n * 64 * 2 + 4096);   // 12.8 MB
    _Float16* hsB  = (_Float16*)carve((size_t)n * 64 * 2 + 4096);   // 12.8 MB
    _Float16* hsC  = (_Float16*)carve((size_t)n * 8 * 2);           // 1.6 MB
    (void)ws_size; (void)n_in; (void)out_size;

    const int binG = (E + BIN_CHUNK - 1) / BIN_CHUNK;   // 782
    const int linG = (n + 255) / 256;                   // 391
    const int aggGrid = (n + 3) / 4;

    // ---- CSR phase 1 || layer-1 linear (independent after dinv decoupling) ----
    (void)hipMemsetAsync(cur, 0, (size_t)NB * 4, stream);
    fat_bin_lin1_kernel<<<binG + linG, 512, 0, stream>>>(
        src, dst, cur, slab, E, NB, binG, x, W1, hsA, n);

    // ---- CSR phase 2 ----
    bucket_sort_kernel<<<NB, 512, 0, stream>>>(slab, cur, srcS, rows, dinv, n);

    // ---- layer 1 aggregation (dinv[src] applied in-loop) ----
    agg64s_kernel<<<aggGrid, 256, 0, stream>>>(hsA, dinv, srcS, rows, b1, hsB, n);

    // ---- layer 2 linear ----
    linear_mfma_f16_kernel<<<(n + 255) / 256, 256, 0, stream>>>(hsB, W2, dinv, hsA, n);

    // ---- layer 2 aggregation + fused W3 projection ----
    agg64w3_kernel<<<aggGrid, 256, 0, stream>>>(hsA, dinv, srcS, rows, b2, W3, (__half*)hsC, n);

    // ---- layer 3 aggregation + log_softmax ----
    agg6_lsm_kernel<<<aggGrid, 256, 0, stream>>>(hsC, dinv, srcS, rows, b3, out, n);
}

// Round 12
// 342.986 us; speedup vs baseline: 1.0357x; 1.0144x over previous
//
#include <hip/hip_runtime.h>
#include <hip/hip_fp16.h>
#include <math.h>

// ---------------------------------------------------------------------------
// GCN 3-layer forward, round 22 (= R18 + bucket||lin1B overlap + fdot2 epilogue).
// out[i] = dinv[i] * ( sum_{e:dst=i} Hs[src] + Hs[i] ) + b,  Hs = (X@W)*dinv.
// Round-22 delta vs round-18 (344.5us best):
//  - lin1 split across BOTH CSR phases: fat1 = bin(782) || lin1-A(196),
//    fat2 = bucket_sort(391) || lin1-B(195). bucket's 391x512t WGs leave
//    ~half the CUs in tail-idle; lin1-B fills them (work-conserving).
//  - agg64w3 epilogue: packed fp16 math. h2 via v_pk ops; W3 projection as
//    6q x 4 v_dot2_f32_f16 vs half2-staged W3 (24 dot2 + 24 conflict-free
//    b32 reads, was 48 FMA + 48 4-way-conflicted reads). R19/R20 showed the
//    epilogue cost is issue slots, not conflicts -> cut the slots.
//  - CSR internals byte-identical to R18 (R21 low-sync was neutral).
// ---------------------------------------------------------------------------

#define WS_ALIGN(x) (((x) + 255) & ~(size_t)255)
#define BKN 256                 // nodes per bin/sort bucket
#define CAP 9216                // slab capacity per bucket (mean 8184; +11 sigma)
#define EPT 8                   // edges per thread in bin kernel
#define BIN_THR 512
#define BIN_CHUNK (BIN_THR * EPT)  // 4096 edges per WG

typedef _Float16 half8 __attribute__((ext_vector_type(8)));
typedef _Float16 half2v __attribute__((ext_vector_type(2)));
typedef float floatx4 __attribute__((ext_vector_type(4)));

// ---------------- lin1 tile body (shared by fat1/fat2 roles) ----------------
__device__ __forceinline__ void lin1_role(
    const float* __restrict__ Xf, const float* __restrict__ W1,
    _Float16* __restrict__ Y, int n, int lblk, int tid, _Float16* Bf) {
    constexpr int K = 128, KC = 4;
    for (int i = tid; i < KC * 4 * 64 * 8; i += 512) {
        int j = i & 7, lane = (i >> 3) & 63, tile = (i >> 9) & 3, kc = i >> 11;
        int k = kc * 32 + ((lane >> 4) << 3) + j;
        int col = tile * 16 + (lane & 15);
        Bf[i] = (_Float16)W1[k * 64 + col];
    }
    __syncthreads();
    const int lane = tid & 63, wid = tid >> 6;   // 8 waves
    const int mrow = lane & 15, quad = lane >> 4;
    #pragma unroll
    for (int tt = 0; tt < 2; ++tt) {             // 8 waves x 2 groups = 256 nodes
        const int base = lblk * 256 + wid * 32 + tt * 16;
        if (base >= n) continue;
        const int anode = min(base + mrow, n - 1);
        floatx4 acc[4] = {{0, 0, 0, 0}, {0, 0, 0, 0}, {0, 0, 0, 0}, {0, 0, 0, 0}};
        #pragma unroll
        for (int kc = 0; kc < KC; ++kc) {
            float4 xa = *(const float4*)&Xf[(size_t)anode * K + kc * 32 + quad * 8];
            float4 xb = *(const float4*)&Xf[(size_t)anode * K + kc * 32 + quad * 8 + 4];
            half8 a;
            a[0] = (_Float16)xa.x; a[1] = (_Float16)xa.y; a[2] = (_Float16)xa.z; a[3] = (_Float16)xa.w;
            a[4] = (_Float16)xb.x; a[5] = (_Float16)xb.y; a[6] = (_Float16)xb.z; a[7] = (_Float16)xb.w;
            #pragma unroll
            for (int t = 0; t < 4; ++t) {
                half8 b = *(const half8*)&Bf[((kc * 4 + t) * 64 + lane) * 8];
                acc[t] = __builtin_amdgcn_mfma_f32_16x16x32_f16(a, b, acc[t], 0, 0, 0);
            }
        }
        #pragma unroll
        for (int r = 0; r < 4; ++r) {
            int node = base + quad * 4 + r;
            if (node < n) {
                #pragma unroll
                for (int t = 0; t < 4; ++t)
                    Y[(size_t)node * 64 + t * 16 + mrow] = (_Float16)acc[t][r];
            }
        }
    }
}

// ---------------- fat1: bin (blocks [0,binG)) || lin1-A ----------------
__global__ __launch_bounds__(512) void fat_bin_lin1_kernel(
    const int* __restrict__ src, const int* __restrict__ dst,
    int* __restrict__ cur, int* __restrict__ slab, int E, int NB, int binG,
    const float* __restrict__ Xf, const float* __restrict__ W1,
    _Float16* __restrict__ Y, int n) {
    __shared__ int smem[5632];   // bin: cnt/incl/gbase[512]x3 + stag[4096] = 22.5KB
    const int tid = threadIdx.x;
    if (blockIdx.x < binG) {
        // ---------------- bin role (R18: LDS counting sort) ----------------
        int* cnt   = smem;
        int* incl  = smem + 512;
        int* gbase = smem + 1024;
        int* stag  = smem + 1536;
        const int base = blockIdx.x * BIN_CHUNK + tid * EPT;
        cnt[tid] = 0;
        __syncthreads();
        int b[EPT], w[EPT], lp[EPT];
        #pragma unroll
        for (int k = 0; k < EPT; ++k) {
            int e = base + k;
            if (e < E) {
                int s = src[e], d = dst[e];
                b[k] = d >> 8;
                w[k] = (s << 8) | (d & 255);
            } else b[k] = -1;
        }
        #pragma unroll
        for (int k = 0; k < EPT; ++k)
            if (b[k] >= 0) lp[k] = atomicAdd(&cnt[b[k]], 1);
        __syncthreads();
        incl[tid] = cnt[tid];
        __syncthreads();
        for (int off = 1; off < 512; off <<= 1) {
            int v = 0;
            if (tid >= off) v = incl[tid - off];
            __syncthreads();
            incl[tid] += v;
            __syncthreads();
        }
        if (tid < NB) {
            int c = cnt[tid];
            gbase[tid] = c ? atomicAdd(&cur[tid], c) : 0;
        }
        #pragma unroll
        for (int k = 0; k < EPT; ++k)
            if (b[k] >= 0) stag[incl[b[k]] - cnt[b[k]] + lp[k]] = w[k];
        __syncthreads();
        const int total = incl[NB - 1];
        for (int idx = tid; idx < total; idx += BIN_THR) {
            int wv = stag[idx];
            int lo = 0, hi = NB - 1;
            while (lo < hi) { int mid = (lo + hi) >> 1; if (incl[mid] > idx) hi = mid; else lo = mid + 1; }
            int excl = incl[lo] - cnt[lo];
            int p = gbase[lo] + (idx - excl);
            if (p < CAP) slab[(size_t)lo * CAP + p] = wv;
        }
    } else {
        lin1_role(Xf, W1, Y, n, blockIdx.x - binG, tid, (_Float16*)smem);
    }
}

// ---------------- fat2: bucket_sort (blocks [0,NB)) || lin1-B ----------------
__global__ __launch_bounds__(512) void fat_bucket_lin1_kernel(
    const int* __restrict__ slab, const int* __restrict__ cur,
    int* __restrict__ srcS, int2* __restrict__ rows,
    float* __restrict__ dinv, int NB, int linBase,
    const float* __restrict__ Xf, const float* __restrict__ W1,
    _Float16* __restrict__ Y, int n) {
    __shared__ int smem[4096];   // lin: 16KB Bf; bucket: cnt/s/cursor (3KB)
    const int tid = threadIdx.x;
    if ((int)blockIdx.x < NB) {
        // ---------------- bucket role (R18 byte-form) ----------------
        int* cnt    = smem;
        int* s      = smem + 256;
        int* cursor = smem + 512;
        const int b = blockIdx.x;
        const int m = min(cur[b], CAP);
        const int* sp = slab + (size_t)b * CAP;
        if (tid < BKN) cnt[tid] = 0;
        __syncthreads();
        for (int j = tid; j < m; j += 512) atomicAdd(&cnt[sp[j] & (BKN - 1)], 1);
        __syncthreads();
        if (tid < BKN) s[tid] = cnt[tid];
        __syncthreads();
        for (int off = 1; off < BKN; off <<= 1) {
            int v = 0;
            if (tid < BKN && tid >= off) v = s[tid - off];
            __syncthreads();
            if (tid < BKN) s[tid] += v;
            __syncthreads();
        }
        if (tid < BKN) {
            int ofs = s[tid] - cnt[tid];
            cursor[tid] = ofs;
            int node = b * BKN + tid;
            if (node < n) {
                rows[node] = make_int2(b * CAP + ofs, b * CAP + ofs + cnt[tid]);
                dinv[node] = rsqrtf((float)(cnt[tid] + 1));
            }
        }
        __syncthreads();
        for (int j = tid; j < m; j += 512) {
            int w = sp[j];
            int p = atomicAdd(&cursor[w & (BKN - 1)], 1);
            srcS[(size_t)b * CAP + p] = w >> 8;
        }
    } else {
        lin1_role(Xf, W1, Y, n, (int)blockIdx.x - NB + linBase, tid, (_Float16*)smem);
    }
}

// ---------------- MFMA linear (fp16 input), K=64, 4 tiles per WG ----------------
__global__ __launch_bounds__(256) void linear_mfma_f16_kernel(
    const _Float16* __restrict__ Xh, const float* __restrict__ W,
    const float* __restrict__ dinv, _Float16* __restrict__ Y, int n) {
    constexpr int K = 64, KC = 2;
    __shared__ _Float16 Bf[KC * 4 * 64 * 8];  // 8KB
    const int tid = threadIdx.x;
    for (int i = tid; i < KC * 4 * 64 * 8; i += 256) {
        int j = i & 7, lane = (i >> 3) & 63, tile = (i >> 9) & 3, kc = i >> 11;
        int k = kc * 32 + ((lane >> 4) << 3) + j;
        int col = tile * 16 + (lane & 15);
        Bf[i] = (_Float16)W[k * 64 + col];
    }
    __syncthreads();
    const int lane = tid & 63, wid = tid >> 6;
    const int mrow = lane & 15, quad = lane >> 4;
    #pragma unroll
    for (int tt = 0; tt < 4; ++tt) {
        const int base = (blockIdx.x * 4 + tt) * 64 + wid * 16;
        if (base >= n) continue;
        const int anode = min(base + mrow, n - 1);
        floatx4 acc[4] = {{0, 0, 0, 0}, {0, 0, 0, 0}, {0, 0, 0, 0}, {0, 0, 0, 0}};
        #pragma unroll
        for (int kc = 0; kc < KC; ++kc) {
            half8 a = *(const half8*)&Xh[(size_t)anode * K + kc * 32 + quad * 8];
            #pragma unroll
            for (int t = 0; t < 4; ++t) {
                half8 b = *(const half8*)&Bf[((kc * 4 + t) * 64 + lane) * 8];
                acc[t] = __builtin_amdgcn_mfma_f32_16x16x32_f16(a, b, acc[t], 0, 0, 0);
            }
        }
        #pragma unroll
        for (int r = 0; r < 4; ++r) {
            int node = base + quad * 4 + r;
            if (node < n) {
                float di = dinv[node];
                #pragma unroll
                for (int t = 0; t < 4; ++t)
                    Y[(size_t)node * 64 + t * 16 + mrow] = (_Float16)(acc[t][r] * di);
            }
        }
    }
}

// ---------------- agg64s (L1): gather UNSCALED h1, scale by dinv[src] in-loop ----------------
__global__ __launch_bounds__(256) void agg64s_kernel(
    const _Float16* __restrict__ H1, const float* __restrict__ dinv,
    const int* __restrict__ srcS, const int2* __restrict__ rows,
    const float* __restrict__ bias, _Float16* __restrict__ Out, int n) {
    const int wave = (blockIdx.x * blockDim.x + threadIdx.x) >> 6;
    const int lane = threadIdx.x & 63;
    if (wave >= n) return;
    const int slot = lane >> 3;  // edge slot 0..7
    const int f8 = lane & 7;     // feat slice [f8*8, f8*8+8)
    const int2 row = rows[wave];
    const int beg = row.x, end = row.y;
    half8 hA, hB;
    #pragma unroll
    for (int i = 0; i < 8; ++i) { hA[i] = (_Float16)0.f; hB[i] = (_Float16)0.f; }
    int j = beg;
    for (; j + 32 <= end; j += 32) {      // 32 edges: 4 gathers in flight
        int s0 = srcS[j      + slot];
        int s1 = srcS[j + 8  + slot];
        int s2 = srcS[j + 16 + slot];
        int s3 = srcS[j + 24 + slot];
        _Float16 d0 = (_Float16)dinv[s0];
        _Float16 d1 = (_Float16)dinv[s1];
        _Float16 d2 = (_Float16)dinv[s2];
        _Float16 d3 = (_Float16)dinv[s3];
        half8 v0 = *(const half8*)&H1[(size_t)s0 * 64 + f8 * 8];
        half8 v1 = *(const half8*)&H1[(size_t)s1 * 64 + f8 * 8];
        half8 v2 = *(const half8*)&H1[(size_t)s2 * 64 + f8 * 8];
        half8 v3 = *(const half8*)&H1[(size_t)s3 * 64 + f8 * 8];
        hA += v0 * d0; hB += v1 * d1; hA += v2 * d2; hB += v3 * d3;
    }
    for (; j + 16 <= end; j += 16) {      // 16 edges
        int s0 = srcS[j + slot];
        int s1 = srcS[j + 8 + slot];
        _Float16 d0 = (_Float16)dinv[s0];
        _Float16 d1 = (_Float16)dinv[s1];
        half8 v0 = *(const half8*)&H1[(size_t)s0 * 64 + f8 * 8];
        half8 v1 = *(const half8*)&H1[(size_t)s1 * 64 + f8 * 8];
        hA += v0 * d0; hB += v1 * d1;
    }
    for (; j < end; j += 8) {             // tail (exec-masked)
        int jj = j + slot;
        if (jj < end) {
            int s0 = srcS[jj];
            _Float16 d0 = (_Float16)dinv[s0];
            half8 v = *(const half8*)&H1[(size_t)s0 * 64 + f8 * 8];
            hA += v * d0;
        }
    }
    half8 ht = hA + hB;
    #pragma unroll
    for (int mask = 8; mask <= 32; mask <<= 1) {  // packed fold over slots
        int4 ci = *(int4*)&ht, oi;
        oi.x = __shfl_xor(ci.x, mask);
        oi.y = __shfl_xor(ci.y, mask);
        oi.z = __shfl_xor(ci.z, mask);
        oi.w = __shfl_xor(ci.w, mask);
        ht += *(half8*)&oi;
    }
    half8 self = *(const half8*)&H1[(size_t)wave * 64 + f8 * 8];
    const float di = dinv[wave];
    float4 b0 = *(const float4*)&bias[f8 * 8];
    float4 b1v = *(const float4*)&bias[f8 * 8 + 4];
    float bb[8] = {b0.x, b0.y, b0.z, b0.w, b1v.x, b1v.y, b1v.z, b1v.w};
    half8 o;
    #pragma unroll
    for (int i = 0; i < 8; ++i) {
        float t = ((float)ht[i] + di * (float)self[i]) * di + bb[i];
        o[i] = (_Float16)fmaxf(t, 0.f);
    }
    if (slot == 0) *(half8*)&Out[(size_t)wave * 64 + f8 * 8] = o;
}

// ---------------- agg64w3 (L2): aggregate + relu -> h2 (fp16), dot2-project W3 ----------------
// h2[f] = relu( (sum_s Hs2[s] + Hs2[i]) * di + b2[f] );  hsC[i][q] = di * sum_f h2[f] W3[f][q]
// W3 staged as half2 pairs W3h[q][j] = {W3[2j][q], W3[2j+1][q]} (768B); b2 as half2 (128B).
__global__ __launch_bounds__(256) void agg64w3_kernel(
    const _Float16* __restrict__ Hs, const float* __restrict__ dinv,
    const int* __restrict__ srcS, const int2* __restrict__ rows,
    const float* __restrict__ bias, const float* __restrict__ W3,
    __half* __restrict__ Yc, int n) {
    __shared__ unsigned int W3h[6 * 32];   // half2 packed, [q][j]
    __shared__ unsigned int B2h[32];       // half2 packed b2 pairs
    const int tid = threadIdx.x;
    for (int i = tid; i < 6 * 32; i += 256) {
        int q = i >> 5, jp = i & 31;
        half2v v;
        v[0] = (_Float16)W3[(2 * jp) * 6 + q];
        v[1] = (_Float16)W3[(2 * jp + 1) * 6 + q];
        W3h[i] = *(unsigned int*)&v;
    }
    if (tid < 32) {
        half2v v;
        v[0] = (_Float16)bias[2 * tid];
        v[1] = (_Float16)bias[2 * tid + 1];
        B2h[tid] = *(unsigned int*)&v;
    }
    __syncthreads();
    const int wave = (blockIdx.x * blockDim.x + tid) >> 6;
    const int lane = tid & 63;
    if (wave >= n) return;
    const int slot = lane >> 3;
    const int f8 = lane & 7;
    const int2 row = rows[wave];
    const int beg = row.x, end = row.y;
    half8 hA, hB;
    #pragma unroll
    for (int i = 0; i < 8; ++i) { hA[i] = (_Float16)0.f; hB[i] = (_Float16)0.f; }
    int j = beg;
    for (; j + 32 <= end; j += 32) {
        int s0 = srcS[j      + slot];
        int s1 = srcS[j + 8  + slot];
        int s2 = srcS[j + 16 + slot];
        int s3 = srcS[j + 24 + slot];
        half8 v0 = *(const half8*)&Hs[(size_t)s0 * 64 + f8 * 8];
        half8 v1 = *(const half8*)&Hs[(size_t)s1 * 64 + f8 * 8];
        half8 v2 = *(const half8*)&Hs[(size_t)s2 * 64 + f8 * 8];
        half8 v3 = *(const half8*)&Hs[(size_t)s3 * 64 + f8 * 8];
        hA += v0; hB += v1; hA += v2; hB += v3;
    }
    for (; j + 16 <= end; j += 16) {
        int s0 = srcS[j + slot];
        int s1 = srcS[j + 8 + slot];
        half8 v0 = *(const half8*)&Hs[(size_t)s0 * 64 + f8 * 8];
        half8 v1 = *(const half8*)&Hs[(size_t)s1 * 64 + f8 * 8];
        hA += v0; hB += v1;
    }
    for (; j < end; j += 8) {
        int jj = j + slot;
        if (jj < end) {
            half8 v = *(const half8*)&Hs[(size_t)srcS[jj] * 64 + f8 * 8];
            hA += v;
        }
    }
    half8 ht = hA + hB;
    #pragma unroll
    for (int mask = 8; mask <= 32; mask <<= 1) {
        int4 ci = *(int4*)&ht, oi;
        oi.x = __shfl_xor(ci.x, mask);
        oi.y = __shfl_xor(ci.y, mask);
        oi.z = __shfl_xor(ci.z, mask);
        oi.w = __shfl_xor(ci.w, mask);
        ht += *(half8*)&oi;
    }
    half8 self = *(const half8*)&Hs[(size_t)wave * 64 + f8 * 8];
    const float di = dinv[wave];
    // h2 = relu((ht+self)*di + b2)  -- packed fp16
    half8 bb8 = *(half8*)&B2h[f8 * 4];      // 16B aligned
    half8 s8 = ht + self;
    half8 t8 = s8 * (_Float16)di + bb8;
    half8 h2;
    #pragma unroll
    for (int i = 0; i < 8; ++i) h2[i] = t8[i] > (_Float16)0.f ? t8[i] : (_Float16)0.f;
    // projection: p[q] = sum over 4 half2 pairs via v_dot2_f32_f16
    float p[6];
    #pragma unroll
    for (int q = 0; q < 6; ++q) {
        float acc = 0.f;
        #pragma unroll
        for (int t = 0; t < 4; ++t) {
            half2v hp;
            hp[0] = h2[2 * t]; hp[1] = h2[2 * t + 1];
            unsigned int wu = W3h[q * 32 + f8 * 4 + t];
            half2v wv = *(half2v*)&wu;
#if defined(__has_builtin)
#if __has_builtin(__builtin_amdgcn_fdot2)
            acc = __builtin_amdgcn_fdot2(hp, wv, acc, false);
#else
            acc += (float)hp[0] * (float)wv[0] + (float)hp[1] * (float)wv[1];
#endif
#else
            acc += (float)hp[0] * (float)wv[0] + (float)hp[1] * (float)wv[1];
#endif
        }
        p[q] = acc;
    }
    #pragma unroll
    for (int mask = 1; mask <= 4; mask <<= 1) {   // fold over f8 (bits 0..2)
        #pragma unroll
        for (int q = 0; q < 6; ++q) p[q] += __shfl_xor(p[q], mask);
    }
    if (lane == 0) {
        half8 o;
        #pragma unroll
        for (int q = 0; q < 6; ++q) o[q] = (_Float16)(p[q] * di);
        o[6] = (_Float16)0.f; o[7] = (_Float16)0.f;
        *(half8*)&Yc[(size_t)wave * 8] = o;
    }
}

// ---------------- aggregate 6 feats + bias + log_softmax: lane-per-edge ----------------
__global__ __launch_bounds__(256) void agg6_lsm_kernel(
    const _Float16* __restrict__ Hs6, const float* __restrict__ dinv,
    const int* __restrict__ srcS, const int2* __restrict__ rows,
    const float* __restrict__ bias, float* __restrict__ out, int n) {
    const int wave = (blockIdx.x * blockDim.x + threadIdx.x) >> 6;
    const int lane = threadIdx.x & 63;
    if (wave >= n) return;
    const int2 row = rows[wave];
    const int beg = row.x, end = row.y;
    half8 ht;
    #pragma unroll
    for (int i = 0; i < 8; ++i) ht[i] = (_Float16)0.f;
    for (int j = beg + lane; j < end; j += 64) {          // 1 iter typ. (deg~32)
        int s = srcS[j];
        ht += *(const half8*)&Hs6[(size_t)s * 8];          // 16B row gather
    }
    #pragma unroll
    for (int mask = 1; mask <= 32; mask <<= 1) {          // packed fold, 64 lanes
        int4 ci = *(int4*)&ht, oi;
        oi.x = __shfl_xor(ci.x, mask);
        oi.y = __shfl_xor(ci.y, mask);
        oi.z = __shfl_xor(ci.z, mask);
        oi.w = __shfl_xor(ci.w, mask);
        ht += *(half8*)&oi;
    }
    half8 self = *(const half8*)&Hs6[(size_t)wave * 8];
    const float di = dinv[wave];
    float a[6];
    #pragma unroll
    for (int q = 0; q < 6; ++q)
        a[q] = ((float)ht[q] + (float)self[q]) * di + bias[q];
    float mx = a[0];
    #pragma unroll
    for (int q = 1; q < 6; ++q) mx = fmaxf(mx, a[q]);
    float sum = 0.f;
    #pragma unroll
    for (int q = 0; q < 6; ++q) sum += expf(a[q] - mx);
    float lse = mx + logf(sum);
    if (lane == 0) {
        float* op = &out[(size_t)wave * 6];
        *(float2*)(op)     = make_float2(a[0] - lse, a[1] - lse);
        *(float2*)(op + 2) = make_float2(a[2] - lse, a[3] - lse);
        *(float2*)(op + 4) = make_float2(a[4] - lse, a[5] - lse);
    }
}

// ---------------------------------------------------------------------------
extern "C" void kernel_launch(void* const* d_in, const int* in_sizes, int n_in,
                              void* d_out, int out_size, void* d_ws, size_t ws_size,
                              hipStream_t stream) {
    const float* x  = (const float*)d_in[0];
    const int*   ei = (const int*)d_in[1];
    const float* W1 = (const float*)d_in[2];
    const float* b1 = (const float*)d_in[3];
    const float* W2 = (const float*)d_in[4];
    const float* b2 = (const float*)d_in[5];
    const float* W3 = (const float*)d_in[6];
    const float* b3 = (const float*)d_in[7];
    float* out = (float*)d_out;

    const int n = in_sizes[0] / 128;  // 100000
    const int E = in_sizes[1] / 2;    // 3200000
    const int* src = ei;
    const int* dst = ei + E;
    const int NB = (n + BKN - 1) / BKN;  // 391

    // ---- workspace carve ----
    char* ws = (char*)d_ws;
    auto carve = [&](size_t bytes) { char* p = ws; ws += WS_ALIGN(bytes); return p; };
    int*      cur  = (int*)     carve((size_t)NB * 4);
    float*    dinv = (float*)   carve((size_t)n * 4);
    int*      slab = (int*)     carve((size_t)NB * CAP * 4);   // 14.4 MB
    int*      srcS = (int*)     carve((size_t)NB * CAP * 4);   // 14.4 MB
    int2*     rows = (int2*)    carve((size_t)n * 8);
    _Float16* hsA  = (_Float16*)carve((size_t)n * 64 * 2 + 4096);   // 12.8 MB
    _Float16* hsB  = (_Float16*)carve((size_t)n * 64 * 2 + 4096);   // 12.8 MB
    _Float16* hsC  = (_Float16*)carve((size_t)n * 8 * 2);           // 1.6 MB
    (void)ws_size; (void)n_in; (void)out_size;

    const int binG = (E + BIN_CHUNK - 1) / BIN_CHUNK;   // 782
    const int linG = (n + 255) / 256;                   // 391
    const int linA = (linG + 1) / 2;                    // 196 (nodes 0..50175)
    const int linB = linG - linA;                       // 195
    const int aggGrid = (n + 3) / 4;

    // ---- CSR phase 1 || lin1-A ----
    (void)hipMemsetAsync(cur, 0, (size_t)NB * 4, stream);
    fat_bin_lin1_kernel<<<binG + linA, 512, 0, stream>>>(
        src, dst, cur, slab, E, NB, binG, x, W1, hsA, n);

    // ---- CSR phase 2 || lin1-B ----
    fat_bucket_lin1_kernel<<<NB + linB, 512, 0, stream>>>(
        slab, cur, srcS, rows, dinv, NB, linA, x, W1, hsA, n);

    // ---- layer 1 aggregation (dinv[src] applied in-loop) ----
    agg64s_kernel<<<aggGrid, 256, 0, stream>>>(hsA, dinv, srcS, rows, b1, hsB, n);

    // ---- layer 2 linear ----
    linear_mfma_f16_kernel<<<(n + 255) / 256, 256, 0, stream>>>(hsB, W2, dinv, hsA, n);

    // ---- layer 2 aggregation + fused W3 projection (dot2 epilogue) ----
    agg64w3_kernel<<<aggGrid, 256, 0, stream>>>(hsA, dinv, srcS, rows, b2, W3, (__half*)hsC, n);

    // ---- layer 3 aggregation + log_softmax ----
    agg6_lsm_kernel<<<aggGrid, 256, 0, stream>>>(hsC, dinv, srcS, rows, b3, out, n);
}